// Round 7
// baseline (1950.518 us; speedup 1.0000x reference)
//
#include <hip/hip_runtime.h>

typedef unsigned short u16;
typedef __attribute__((ext_vector_type(8))) short bf16x8;
typedef __attribute__((ext_vector_type(4))) float f32x4;

__device__ inline u16 f2bf(float f) {
  unsigned int u = __float_as_uint(f);
  u += 0x7fffu + ((u >> 16) & 1u);
  return (u16)(u >> 16);
}
__device__ inline float bf2f(u16 v) {
  return __uint_as_float((unsigned)v << 16);
}

__device__ inline uint4 pack8(float4 a, float4 b) {
  uint4 r;
  r.x = (unsigned)f2bf(a.x) | ((unsigned)f2bf(a.y) << 16);
  r.y = (unsigned)f2bf(a.z) | ((unsigned)f2bf(a.w) << 16);
  r.z = (unsigned)f2bf(b.x) | ((unsigned)f2bf(b.y) << 16);
  r.w = (unsigned)f2bf(b.z) | ((unsigned)f2bf(b.w) << 16);
  return r;
}

__device__ inline void atomic_pk_add_bf16(u16* p, unsigned v) {
  asm volatile("global_atomic_pk_add_bf16 %0, %1, off" : : "v"(p), "v"(v)
               : "memory");
}

// ---- fused one-shot weight transpose: dst[c*R+r] = bf16(src[r*C+c]) ----
struct TransDesc {
  const float* src[9];
  u16* dst[9];
  int R[9];
  int C[9];
  int pre[10];
};

__global__ void transpose_all_kernel(TransDesc td) {
  int t = blockIdx.x * 256 + threadIdx.x;
  if (t >= td.pre[9]) return;
  int seg = 0;
  while (t >= td.pre[seg + 1]) ++seg;
  int local = t - td.pre[seg];
  int C = td.C[seg], R = td.R[seg];
  int r = local / C, c = local - r * C;
  td.dst[seg][(size_t)c * R + r] = f2bf(td.src[seg][local]);
}

__global__ void bf16_to_f32_kernel(const u16* __restrict__ in,
                                   float* __restrict__ out, int n8) {
  int t = blockIdx.x * 256 + threadIdx.x;
  if (t < n8) {
    uint4 v = ((const uint4*)in)[t];
    u16* p = (u16*)&v;
    float4 o0 = {bf2f(p[0]), bf2f(p[1]), bf2f(p[2]), bf2f(p[3])};
    float4 o1 = {bf2f(p[4]), bf2f(p[5]), bf2f(p[6]), bf2f(p[7])};
    ((float4*)out)[t * 2] = o0;
    ((float4*)out)[t * 2 + 1] = o1;
  }
}

// ---------------- CSR build ----------------
__global__ void count_kernel(const int* __restrict__ fi,
                             const int* __restrict__ ti,
                             int* __restrict__ cnt, int E) {
  int e = blockIdx.x * 256 + threadIdx.x;
  if (e < E) {
    atomicAdd(&cnt[ti[e]], 1);
    atomicAdd(&cnt[fi[e]], 1);
  }
}

__global__ void scan1_kernel(const int* __restrict__ cnt,
                             int* __restrict__ partial, int N, int chunk) {
  __shared__ int sdata[256];
  int b = blockIdx.x, t = threadIdx.x;
  int base = b * chunk;
  int sum = 0;
  for (int i = t; i < chunk; i += 256) {
    int idx = base + i;
    if (idx < N) sum += cnt[idx];
  }
  sdata[t] = sum;
  __syncthreads();
  for (int s2 = 128; s2 > 0; s2 >>= 1) {
    if (t < s2) sdata[t] += sdata[t + s2];
    __syncthreads();
  }
  if (t == 0) partial[b] = sdata[0];
}

__global__ void scan2_kernel(int* __restrict__ partial, int* __restrict__ off,
                             int N) {
  __shared__ int s[256];
  int t = threadIdx.x;
  int own = partial[t];
  s[t] = own;
  __syncthreads();
  for (int d2 = 1; d2 < 256; d2 <<= 1) {
    int v = (t >= d2) ? s[t - d2] : 0;
    __syncthreads();
    s[t] += v;
    __syncthreads();
  }
  partial[t] = s[t] - own;
  if (t == 255) off[N] = s[255];
}

__global__ void scan3_kernel(const int* __restrict__ cnt,
                             const int* __restrict__ partialEx,
                             int* __restrict__ off, int* __restrict__ cursor,
                             int N, int chunk) {
  __shared__ int s[256];
  int b = blockIdx.x, t = threadIdx.x;
  int base = b * chunk;
  int own = (t < chunk && base + t < N) ? cnt[base + t] : 0;
  s[t] = own;
  __syncthreads();
  for (int d2 = 1; d2 < 256; d2 <<= 1) {
    int v = (t >= d2) ? s[t - d2] : 0;
    __syncthreads();
    s[t] += v;
    __syncthreads();
  }
  int ex = s[t] - own + partialEx[b];
  if (t < chunk && base + t < N) {
    off[base + t] = ex;
    cursor[base + t] = ex;
  }
}

__global__ void pos_kernel(const int* __restrict__ fi,
                           const int* __restrict__ ti, int* __restrict__ cursor,
                           int* __restrict__ pos0, int* __restrict__ pos1,
                           int E) {
  int e = blockIdx.x * 256 + threadIdx.x;
  if (e < E) {
    pos0[e] = atomicAdd(&cursor[ti[e]], 1);
    pos1[e] = atomicAdd(&cursor[fi[e]], 1);
  }
}

// segment sum: one wave per node, contiguous msg rows, f32, 4-deep ILP
__global__ __launch_bounds__(256) void agg_csr_kernel(
    const u16* __restrict__ msg, const int* __restrict__ off,
    float* __restrict__ aggf, int N) {
  int n = blockIdx.x * 4 + (threadIdx.x >> 6);
  if (n >= N) return;
  int lane = threadIdx.x & 63;
  int s = off[n], e = off[n + 1];
  const unsigned* m32 = (const unsigned*)msg;
  float a0 = 0.f, a1 = 0.f, b0 = 0.f, b1 = 0.f;
  float c0 = 0.f, c1 = 0.f, d0 = 0.f, d1 = 0.f;
  int r = s;
  for (; r + 3 < e; r += 4) {
    unsigned x0 = m32[(size_t)r * 64 + lane];
    unsigned x1 = m32[(size_t)(r + 1) * 64 + lane];
    unsigned x2 = m32[(size_t)(r + 2) * 64 + lane];
    unsigned x3 = m32[(size_t)(r + 3) * 64 + lane];
    a0 += bf2f((u16)(x0 & 0xffff)); a1 += bf2f((u16)(x0 >> 16));
    b0 += bf2f((u16)(x1 & 0xffff)); b1 += bf2f((u16)(x1 >> 16));
    c0 += bf2f((u16)(x2 & 0xffff)); c1 += bf2f((u16)(x2 >> 16));
    d0 += bf2f((u16)(x3 & 0xffff)); d1 += bf2f((u16)(x3 >> 16));
  }
  for (; r < e; ++r) {
    unsigned x0 = m32[(size_t)r * 64 + lane];
    a0 += bf2f((u16)(x0 & 0xffff)); a1 += bf2f((u16)(x0 >> 16));
  }
  aggf[(size_t)n * 128 + lane * 2] = (a0 + b0) + (c0 + d0);
  aggf[(size_t)n * 128 + lane * 2 + 1] = (a1 + b1) + (c1 + d1);
}

// ---- shared MFMA helpers (verified R1-R6) ----
__device__ inline void stage_w_rw(u16* sW, const u16* __restrict__ src,
                                  int roww, int colofs, int tid) {
  int n = tid >> 1, half = tid & 1;
  const u16* s = src + (size_t)n * roww + colofs + half * 64;
#pragma unroll
  for (int q = 0; q < 8; ++q) {
    uint4 v = *(const uint4*)(s + q * 8);
    int byte = n * 256 + ((half * 128 + q * 16) ^ ((n & 7) << 4));
    *(uint4*)((char*)sW + byte) = v;
  }
}

__device__ inline void mfma_pass(const u16* A, const u16* W, f32x4 acc[8],
                                 int w, int lane) {
  const int cA = lane & 15;
  const int ko = (lane >> 4) * 8;
  const int arow = 16 * w + cA;
#pragma unroll
  for (int kk = 0; kk < 4; ++kk) {
    int ka = (kk * 32 + ko) * 2;
    int sx = ka ^ ((cA & 7) << 4);
    bf16x8 a = *(const bf16x8*)((const char*)A + arow * 256 + sx);
#pragma unroll
    for (int nt = 0; nt < 8; ++nt) {
      bf16x8 bb = *(const bf16x8*)((const char*)W + (nt * 16 + cA) * 256 + sx);
      acc[nt] = __builtin_amdgcn_mfma_f32_16x16x32_bf16(a, bb, acc[nt], 0, 0, 0);
    }
  }
}

__device__ inline void write_h_lds(u16* sH, const f32x4 acc[8], int w,
                                   int lane) {
#pragma unroll
  for (int nt = 0; nt < 8; ++nt) {
    int col = nt * 16 + (lane & 15);
#pragma unroll
    for (int i = 0; i < 4; ++i) {
      int rr = 16 * w + ((lane >> 4) * 4) + i;
      *(u16*)((char*)sH + rr * 256 + ((col * 2) ^ ((rr & 7) << 4))) =
          f2bf(acc[nt][i]);
    }
  }
}

// Pa = bf16(ns @ W1a), Pb = bf16(ns @ W1b)
__global__ __launch_bounds__(256) void node_partial_kernel(
    const float* __restrict__ ns, const u16* __restrict__ Wt1,
    u16* __restrict__ Pa, u16* __restrict__ Pb, int N) {
  __shared__ u16 sA[64 * 128];
  __shared__ u16 sW[128 * 128];
  const int tid = threadIdx.x;
  const int lane = tid & 63;
  const int w = tid >> 6;
  const int r0 = blockIdx.x * 64;
  {
    int row = tid >> 2, seg = tid & 3;
    int rr = r0 + row;
    if (rr >= N) rr = N - 1;
    const float4* sx = (const float4*)(ns + (size_t)rr * 128 + seg * 32);
#pragma unroll
    for (int q = 0; q < 4; ++q) {
      int byte = row * 256 + ((seg * 64 + q * 16) ^ ((row & 7) << 4));
      *(uint4*)((char*)sA + byte) = pack8(sx[q * 2], sx[q * 2 + 1]);
    }
  }
  stage_w_rw(sW, Wt1, 384, 0, tid);
  __syncthreads();
  f32x4 accA[8] = {};
  mfma_pass(sA, sW, accA, w, lane);
  __syncthreads();
  stage_w_rw(sW, Wt1, 384, 128, tid);
  __syncthreads();
  f32x4 accB[8] = {};
  mfma_pass(sA, sW, accB, w, lane);
#pragma unroll
  for (int nt = 0; nt < 8; ++nt) {
    int col = nt * 16 + (lane & 15);
#pragma unroll
    for (int i = 0; i < 4; ++i) {
      int rr = 16 * w + ((lane >> 4) * 4) + i;
      int row = r0 + rr;
      if (row < N) {
        Pa[(size_t)row * 128 + col] = f2bf(accA[nt][i]);
        Pb[(size_t)row * 128 + col] = f2bf(accB[nt][i]);
      }
    }
  }
}

// ---- SLIM fused edge MLP: 256 threads, 32 edges/tile (64 rows), no pinned
// weights (B-frags direct from L2-hot global), wave-private rows -> only
// 3 barriers/tile. LDS 16.5 KB, target 4-5 waves/SIMD.
__global__ __launch_bounds__(256, 4) void edge_slim_kernel(
    const float* __restrict__ ef, const int* __restrict__ from_idx,
    const int* __restrict__ to_idx, const u16* __restrict__ Wt1,
    const u16* __restrict__ Wt2, const u16* __restrict__ Wt3,
    const u16* __restrict__ Pa, const u16* __restrict__ Pb,
    const float* __restrict__ b1, const float* __restrict__ b2,
    const float* __restrict__ b3, const int* __restrict__ pos0,
    const int* __restrict__ pos1, u16* __restrict__ msg, int E, int ntiles) {
  __shared__ u16 sH[64 * 128];  // 16 KB
  __shared__ int sPos[64];
  const int tid = threadIdx.x;
  const int lane = tid & 63;
  const int wv = tid >> 6;       // 0..3
  const int l15 = lane & 15;
  const int lhi = lane >> 4;
  const int wrow = wv & 1;       // phase-A row half
  const int wcol = wv >> 1;      // phase-A col half

  // biases (per-lane)
  float b1f[4], b2f[8], b3f[8];
#pragma unroll
  for (int nt = 0; nt < 4; ++nt) b1f[nt] = b1[(wcol << 6) + (nt << 4) + l15];
#pragma unroll
  for (int nt = 0; nt < 8; ++nt) {
    b2f[nt] = b2[(nt << 4) + l15];
    b3f[nt] = b3[(nt << 4) + l15];
  }

  for (int t = blockIdx.x; t < ntiles; t += gridDim.x) {
    const int e0 = t << 5;  // 32 edges
    // pos prefetch (rows 0..31 dir0 -> pos0, 32..63 dir1 -> pos1)
    if (tid < 64) {
      int er = tid & 31;
      int e = e0 + er;
      sPos[tid] = (e < E) ? ((tid < 32) ? pos0[e] : pos1[e]) : -1;
    }
    // Phase A: EF = ef@W1c + b1 for 32 edges; wave covers 16 rows x 64 cols
    {
      int arow = (wrow << 4) + l15;
      int e = e0 + arow;
      if (e >= E) e = E - 1;
      const float* ep = ef + (size_t)e * 128 + (lhi << 3);
      f32x4 a1[4] = {};
#pragma unroll
      for (int kk = 0; kk < 4; ++kk) {
        float4 f0 = *(const float4*)(ep + (kk << 5));
        float4 f1 = *(const float4*)(ep + (kk << 5) + 4);
        uint4 u = pack8(f0, f1);
        bf16x8 av = *(bf16x8*)&u;
#pragma unroll
        for (int nt = 0; nt < 4; ++nt) {
          int c = (wcol << 6) + (nt << 4) + l15;
          bf16x8 bb = *(const bf16x8*)(Wt1 + (size_t)c * 384 + 256 + (kk << 5) + (lhi << 3));
          a1[nt] = __builtin_amdgcn_mfma_f32_16x16x32_bf16(av, bb, a1[nt], 0, 0, 0);
        }
      }
#pragma unroll
      for (int nt = 0; nt < 4; ++nt) {
        int col = (wcol << 6) + (nt << 4) + l15;
#pragma unroll
        for (int i = 0; i < 4; ++i) {
          int row = (wrow << 4) + (lhi << 2) + i;
          u16 val = f2bf(a1[nt][i] + b1f[nt]);
          int sw = (col * 2) ^ ((row & 7) << 4);
          *(u16*)((char*)sH + row * 256 + sw) = val;
          *(u16*)((char*)sH + (row + 32) * 256 + sw) = val;
        }
      }
    }
    __syncthreads();  // B1: EF ready block-wide
    // Phase C: sH[row] = relu(sH[row] + Pa[srcA] + Pb[srcB])
#pragma unroll
    for (int it = 0; it < 4; ++it) {
      int task = tid + (it << 8);
      int row = task >> 4;  // 0..63
      int c8 = task & 15;
      int er = row & 31, d = row >> 5;
      int ec = e0 + er;
      if (ec >= E) ec = E - 1;
      int fi_e = from_idx[ec], ti_e = to_idx[ec];
      int sA = d ? ti_e : fi_e;
      int sB = d ? fi_e : ti_e;
      char* hptr = (char*)sH + row * 256 + ((c8 << 4) ^ ((row & 7) << 4));
      uint4 efv = *(const uint4*)hptr;
      uint4 pav = *(const uint4*)(Pa + (size_t)sA * 128 + (c8 << 3));
      uint4 pbv = *(const uint4*)(Pb + (size_t)sB * 128 + (c8 << 3));
      const u16* pe = (const u16*)&efv;
      const u16* pa = (const u16*)&pav;
      const u16* pb = (const u16*)&pbv;
      unsigned o[4];
#pragma unroll
      for (int j = 0; j < 4; ++j) {
        float v0 = fmaxf(bf2f(pe[2 * j]) + bf2f(pa[2 * j]) + bf2f(pb[2 * j]), 0.f);
        float v1 = fmaxf(bf2f(pe[2 * j + 1]) + bf2f(pa[2 * j + 1]) + bf2f(pb[2 * j + 1]), 0.f);
        o[j] = (unsigned)f2bf(v0) | ((unsigned)f2bf(v1) << 16);
      }
      *(uint4*)hptr = *(uint4*)o;
    }
    __syncthreads();  // B2: H1 ready block-wide
    // Phase D: acc = H1 @ W2 (wave-private rows wv*16..+15, B from global)
    const int ra = (wv << 4) + l15;
    bf16x8 hA[4];
#pragma unroll
    for (int kk = 0; kk < 4; ++kk) {
      int sx = ((kk << 6) + (lhi << 4)) ^ ((ra & 7) << 4);
      hA[kk] = *(const bf16x8*)((const char*)sH + ra * 256 + sx);
    }
    f32x4 acc[8] = {};
#pragma unroll
    for (int kk = 0; kk < 4; ++kk) {
#pragma unroll
      for (int nt = 0; nt < 8; ++nt) {
        bf16x8 bb = *(const bf16x8*)(Wt2 + (size_t)((nt << 4) + l15) * 128 + (kk << 5) + (lhi << 3));
        acc[nt] = __builtin_amdgcn_mfma_f32_16x16x32_bf16(hA[kk], bb, acc[nt], 0, 0, 0);
      }
    }
    // Phase E: H2 = relu(acc + b2) -> own rows (within-wave order, no barrier)
#pragma unroll
    for (int nt = 0; nt < 8; ++nt) {
      int col = (nt << 4) + l15;
#pragma unroll
      for (int i = 0; i < 4; ++i) {
        int rl = (wv << 4) + (lhi << 2) + i;
        float v = fmaxf(acc[nt][i] + b2f[nt], 0.f);
        *(u16*)((char*)sH + rl * 256 + ((col * 2) ^ ((rl & 7) << 4))) = f2bf(v);
        acc[nt][i] = 0.f;
      }
    }
    // Phase F: acc = H2 @ W3 (own rows)
#pragma unroll
    for (int kk = 0; kk < 4; ++kk) {
      int sx = ((kk << 6) + (lhi << 4)) ^ ((ra & 7) << 4);
      hA[kk] = *(const bf16x8*)((const char*)sH + ra * 256 + sx);
    }
#pragma unroll
    for (int kk = 0; kk < 4; ++kk) {
#pragma unroll
      for (int nt = 0; nt < 8; ++nt) {
        bf16x8 bb = *(const bf16x8*)(Wt3 + (size_t)((nt << 4) + l15) * 128 + (kk << 5) + (lhi << 3));
        acc[nt] = __builtin_amdgcn_mfma_f32_16x16x32_bf16(hA[kk], bb, acc[nt], 0, 0, 0);
      }
    }
    // OUT = acc + b3 -> own rows in sH (within-wave order OK)
#pragma unroll
    for (int nt = 0; nt < 8; ++nt) {
      int col = (nt << 4) + l15;
#pragma unroll
      for (int i = 0; i < 4; ++i) {
        int rl = (wv << 4) + (lhi << 2) + i;
        *(u16*)((char*)sH + rl * 256 + ((col * 2) ^ ((rl & 7) << 4))) =
            f2bf(acc[nt][i] + b3f[nt]);
      }
    }
    // copy-out own wave's 16 rows, coalesced 16B chunks
#pragma unroll
    for (int it = 0; it < 4; ++it) {
      int row = (wv << 4) + (lane >> 4) + (it << 2);
      int c8 = lane & 15;
      int p = sPos[row];
      if (p >= 0) {
        uint4 v = *(const uint4*)((const char*)sH + row * 256 +
                                  ((c8 << 4) ^ ((row & 7) << 4)));
        *(uint4*)(msg + (size_t)p * 128 + (c8 << 3)) = v;
      }
    }
    __syncthreads();  // B3: sH/sPos free for next tile
  }
}

// ---- atomic fallback (R5-verified) ----
__global__ __launch_bounds__(512, 2) void edge_atomic_kernel(
    const float* __restrict__ ef, const int* __restrict__ from_idx,
    const int* __restrict__ to_idx, const u16* __restrict__ Wt1,
    const u16* __restrict__ Wt2, const u16* __restrict__ Wt3,
    const u16* __restrict__ Pa, const u16* __restrict__ Pb,
    const float* __restrict__ b1, const float* __restrict__ b2,
    const float* __restrict__ b3, u16* __restrict__ aggb, int E, int ntiles) {
  __shared__ u16 sW1c[128 * 128];
  __shared__ u16 sH[128 * 128];
  const int tid = threadIdx.x;
  const int lane = tid & 63;
  const int wv = tid >> 6;
  const int mw = wv >> 1;
  const int nw = wv & 1;
  const int dir = mw >> 1;
  const int l15 = lane & 15;
  const int lhi = lane >> 4;

  {
    int n = tid >> 2, quarter = tid & 3;
    const u16* s = Wt1 + (size_t)n * 384 + 256 + quarter * 32;
#pragma unroll
    for (int q = 0; q < 4; ++q) {
      uint4 v = *(const uint4*)(s + q * 8);
      int byte = n * 256 + ((quarter * 64 + q * 16) ^ ((n & 7) << 4));
      *(uint4*)((char*)sW1c + byte) = v;
    }
  }
  float b1f[4], b2f[4], b3f[4];
#pragma unroll
  for (int nt = 0; nt < 4; ++nt) {
    int col = (nw << 6) + (nt << 4) + l15;
    b1f[nt] = b1[col];
    b2f[nt] = b2[col];
    b3f[nt] = b3[col];
  }
  bf16x8 w2f[4][4], w3f[4][4];
#pragma unroll
  for (int nt = 0; nt < 4; ++nt) {
    int c = (nw << 6) + (nt << 4) + l15;
#pragma unroll
    for (int kk = 0; kk < 4; ++kk) {
      w2f[nt][kk] = *(const bf16x8*)(Wt2 + (size_t)c * 128 + (kk << 5) + (lhi << 3));
      w3f[nt][kk] = *(const bf16x8*)(Wt3 + (size_t)c * 128 + (kk << 5) + (lhi << 3));
    }
  }
  __syncthreads();

  for (int t = blockIdx.x; t < ntiles; t += gridDim.x) {
    const int e0 = t << 6;
    {
      const int arow = (mw << 4) + l15;
      int e = e0 + arow;
      if (e >= E) e = E - 1;
      const float* ep = ef + (size_t)e * 128 + (lhi << 3);
      bf16x8 efA[4];
#pragma unroll
      for (int kk = 0; kk < 4; ++kk) {
        float4 f0 = *(const float4*)(ep + (kk << 5));
        float4 f1 = *(const float4*)(ep + (kk << 5) + 4);
        uint4 u = pack8(f0, f1);
        efA[kk] = *(bf16x8*)&u;
      }
      f32x4 a1[4] = {};
#pragma unroll
      for (int kk = 0; kk < 4; ++kk) {
#pragma unroll
        for (int nt = 0; nt < 4; ++nt) {
          int c = (nw << 6) + (nt << 4) + l15;
          int sx = ((kk << 6) + (lhi << 4)) ^ ((c & 7) << 4);
          bf16x8 bb = *(const bf16x8*)((const char*)sW1c + c * 256 + sx);
          a1[nt] = __builtin_amdgcn_mfma_f32_16x16x32_bf16(efA[kk], bb, a1[nt], 0, 0, 0);
        }
      }
#pragma unroll
      for (int nt = 0; nt < 4; ++nt) {
        int col = (nw << 6) + (nt << 4) + l15;
#pragma unroll
        for (int i = 0; i < 4; ++i) {
          int row = (mw << 4) + (lhi << 2) + i;
          u16 val = f2bf(a1[nt][i] + b1f[nt]);
          int sw = (col * 2) ^ ((row & 7) << 4);
          *(u16*)((char*)sH + row * 256 + sw) = val;
          *(u16*)((char*)sH + (row + 64) * 256 + sw) = val;
        }
      }
    }
    __syncthreads();
#pragma unroll
    for (int it = 0; it < 4; ++it) {
      int row = (tid >> 4) + (it << 5);
      int c8 = tid & 15;
      int er = row & 63, d = row >> 6;
      int ec = e0 + er;
      if (ec >= E) ec = E - 1;
      int fi_e = from_idx[ec], ti_e = to_idx[ec];
      int sA = d ? ti_e : fi_e;
      int sB = d ? fi_e : ti_e;
      char* hptr = (char*)sH + row * 256 + ((c8 << 4) ^ ((row & 7) << 4));
      uint4 efv = *(const uint4*)hptr;
      uint4 pav = *(const uint4*)(Pa + (size_t)sA * 128 + (c8 << 3));
      uint4 pbv = *(const uint4*)(Pb + (size_t)sB * 128 + (c8 << 3));
      const u16* pe = (const u16*)&efv;
      const u16* pa = (const u16*)&pav;
      const u16* pb = (const u16*)&pbv;
      unsigned o[4];
#pragma unroll
      for (int j = 0; j < 4; ++j) {
        float v0 = fmaxf(bf2f(pe[2 * j]) + bf2f(pa[2 * j]) + bf2f(pb[2 * j]), 0.f);
        float v1 = fmaxf(bf2f(pe[2 * j + 1]) + bf2f(pa[2 * j + 1]) + bf2f(pb[2 * j + 1]), 0.f);
        o[j] = (unsigned)f2bf(v0) | ((unsigned)f2bf(v1) << 16);
      }
      *(uint4*)hptr = *(uint4*)o;
    }
    __syncthreads();
    bf16x8 hA[2][4];
#pragma unroll
    for (int m = 0; m < 2; ++m) {
      int ra = (mw << 5) + (m << 4) + l15;
#pragma unroll
      for (int kk = 0; kk < 4; ++kk) {
        int sx = ((kk << 6) + (lhi << 4)) ^ ((ra & 7) << 4);
        hA[m][kk] = *(const bf16x8*)((const char*)sH + ra * 256 + sx);
      }
    }
    f32x4 acc2[2][4] = {};
#pragma unroll
    for (int kk = 0; kk < 4; ++kk)
#pragma unroll
      for (int nt = 0; nt < 4; ++nt)
#pragma unroll
        for (int m = 0; m < 2; ++m)
          acc2[m][nt] = __builtin_amdgcn_mfma_f32_16x16x32_bf16(
              hA[m][kk], w2f[nt][kk], acc2[m][nt], 0, 0, 0);
    __syncthreads();
#pragma unroll
    for (int m = 0; m < 2; ++m) {
#pragma unroll
      for (int i = 0; i < 4; ++i) {
        int rl = (mw << 5) + (m << 4) + (lhi << 2) + i;
#pragma unroll
        for (int nt = 0; nt < 4; ++nt) {
          int col = (nw << 6) + (nt << 4) + l15;
          float v = fmaxf(acc2[m][nt][i] + b2f[nt], 0.f);
          *(u16*)((char*)sH + rl * 256 + ((col * 2) ^ ((rl & 7) << 4))) = f2bf(v);
        }
      }
    }
    __syncthreads();
#pragma unroll
    for (int m = 0; m < 2; ++m) {
      int ra = (mw << 5) + (m << 4) + l15;
#pragma unroll
      for (int kk = 0; kk < 4; ++kk) {
        int sx = ((kk << 6) + (lhi << 4)) ^ ((ra & 7) << 4);
        hA[m][kk] = *(const bf16x8*)((const char*)sH + ra * 256 + sx);
      }
    }
    f32x4 acc3[2][4] = {};
#pragma unroll
    for (int kk = 0; kk < 4; ++kk)
#pragma unroll
      for (int nt = 0; nt < 4; ++nt)
#pragma unroll
        for (int m = 0; m < 2; ++m)
          acc3[m][nt] = __builtin_amdgcn_mfma_f32_16x16x32_bf16(
              hA[m][kk], w3f[nt][kk], acc3[m][nt], 0, 0, 0);
#pragma unroll
    for (int m = 0; m < 2; ++m) {
#pragma unroll
      for (int i = 0; i < 4; ++i) {
        int er = ((mw & 1) << 5) + (m << 4) + (lhi << 2) + i;
        int e = e0 + er;
#pragma unroll
        for (int nt = 0; nt < 4; ++nt) {
          int col = (nw << 6) + (nt << 4) + l15;
          float v = acc3[m][nt][i] + b3f[nt];
          float vp = __shfl_xor(v, 1);
          if (e < E && !(lane & 1)) {
            int dest = dir ? from_idx[e] : to_idx[e];
            unsigned d2 = (unsigned)f2bf(v) | ((unsigned)f2bf(vp) << 16);
            atomic_pk_add_bf16(aggb + (size_t)dest * 128 + col, d2);
          }
        }
      }
    }
    __syncthreads();
  }
}

// Fused 3-GRU chain (verified R5)
__global__ __launch_bounds__(256, 2) void gru3_kernel(
    const float* __restrict__ ns, const float* __restrict__ aggf,
    const u16* __restrict__ g0W, const u16* __restrict__ g0U,
    const u16* __restrict__ g1W, const u16* __restrict__ g1U,
    const u16* __restrict__ g2W, const u16* __restrict__ g2U,
    const float* __restrict__ b0, const float* __restrict__ c0,
    const float* __restrict__ b1, const float* __restrict__ c1,
    const float* __restrict__ b2, const float* __restrict__ c2,
    float* __restrict__ out, int N) {
  __shared__ u16 sX[64 * 128];
  __shared__ u16 sG[64 * 128];
  __shared__ u16 sW[128 * 128];
  const int tid = threadIdx.x;
  const int lane = tid & 63;
  const int w = tid >> 6;
  const int r0 = blockIdx.x * 64;
  {
    int row = tid >> 2, seg = tid & 3;
    int rr = r0 + row;
    if (rr >= N) rr = N - 1;
    const float4* sx = (const float4*)(ns + (size_t)rr * 128 + seg * 32);
    const float4* sh = (const float4*)(aggf + (size_t)rr * 128 + seg * 32);
#pragma unroll
    for (int q = 0; q < 4; ++q) {
      int byte = row * 256 + ((seg * 64 + q * 16) ^ ((row & 7) << 4));
      *(uint4*)((char*)sX + byte) = pack8(sx[q * 2], sx[q * 2 + 1]);
      *(uint4*)((char*)sG + byte) = pack8(sh[q * 2], sh[q * 2 + 1]);
    }
  }

  float hpf[8][4];

#define GPASS(SRC, ABUF, ACC)                       \
  __syncthreads();                                  \
  stage_w_rw(sW, (SRC), 128, 0, tid);               \
  __syncthreads();                                  \
  mfma_pass((ABUF), sW, (ACC), w, lane);

  {
    f32x4 ar[8] = {}, az[8] = {}, ai[8] = {}, ah[8] = {};
    GPASS(g0W + 0 * 16384, sX, ar)
    GPASS(g0U + 0 * 16384, sG, ar)
    GPASS(g0W + 1 * 16384, sX, az)
    GPASS(g0U + 1 * 16384, sG, az)
    GPASS(g0W + 2 * 16384, sX, ai)
    GPASS(g0U + 2 * 16384, sG, ah)
    f32x4 h1[8];
#pragma unroll
    for (int nt = 0; nt < 8; ++nt) {
      int col = nt * 16 + (lane & 15);
      float brc = b0[col] + c0[col];
      float bzc = b0[128 + col] + c0[128 + col];
      float bi = b0[256 + col];
      float bc2 = c0[256 + col];
#pragma unroll
      for (int i = 0; i < 4; ++i) {
        int rloc = 16 * w + ((lane >> 4) * 4) + i;
        int row = r0 + rloc;
        int rowc = row < N ? row : N - 1;
        float hf = aggf[(size_t)rowc * 128 + col];
        float rg = 1.f / (1.f + __expf(-(ar[nt][i] + brc)));
        float zg = 1.f / (1.f + __expf(-(az[nt][i] + bzc)));
        float pre = ai[nt][i] + bi + rg * (ah[nt][i] + bc2);
        float ng = 2.f / (1.f + __expf(-2.f * pre)) - 1.f;
        float hv = (1.f - zg) * ng + zg * hf;
        h1[nt][i] = hv;
        hpf[nt][i] = hv;
      }
    }
    write_h_lds(sX, h1, w, lane);
  }
  {
    f32x4 ar[8] = {}, az[8] = {}, ai[8] = {}, ah[8] = {};
    GPASS(g1W + 0 * 16384, sG, ar)
    GPASS(g1U + 0 * 16384, sX, ar)
    GPASS(g1W + 1 * 16384, sG, az)
    GPASS(g1U + 1 * 16384, sX, az)
    GPASS(g1W + 2 * 16384, sG, ai)
    GPASS(g1U + 2 * 16384, sX, ah)
    f32x4 h2[8];
#pragma unroll
    for (int nt = 0; nt < 8; ++nt) {
      int col = nt * 16 + (lane & 15);
      float brc = b1[col] + c1[col];
      float bzc = b1[128 + col] + c1[128 + col];
      float bi = b1[256 + col];
      float bc2 = c1[256 + col];
#pragma unroll
      for (int i = 0; i < 4; ++i) {
        float rg = 1.f / (1.f + __expf(-(ar[nt][i] + brc)));
        float zg = 1.f / (1.f + __expf(-(az[nt][i] + bzc)));
        float pre = ai[nt][i] + bi + rg * (ah[nt][i] + bc2);
        float ng = 2.f / (1.f + __expf(-2.f * pre)) - 1.f;
        float hv = (1.f - zg) * ng + zg * hpf[nt][i];
        h2[nt][i] = hv;
        hpf[nt][i] = hv;
      }
    }
    write_h_lds(sG, h2, w, lane);
  }
  {
    f32x4 ar[8] = {}, az[8] = {}, ai[8] = {}, ah[8] = {};
    GPASS(g2W + 0 * 16384, sX, ar)
    GPASS(g2U + 0 * 16384, sG, ar)
    GPASS(g2W + 1 * 16384, sX, az)
    GPASS(g2U + 1 * 16384, sG, az)
    GPASS(g2W + 2 * 16384, sX, ai)
    GPASS(g2U + 2 * 16384, sG, ah)
#pragma unroll
    for (int nt = 0; nt < 8; ++nt) {
      int col = nt * 16 + (lane & 15);
      float brc = b2[col] + c2[col];
      float bzc = b2[128 + col] + c2[128 + col];
      float bi = b2[256 + col];
      float bc2 = c2[256 + col];
#pragma unroll
      for (int i = 0; i < 4; ++i) {
        int rloc = 16 * w + ((lane >> 4) * 4) + i;
        int row = r0 + rloc;
        if (row < N) {
          float rg = 1.f / (1.f + __expf(-(ar[nt][i] + brc)));
          float zg = 1.f / (1.f + __expf(-(az[nt][i] + bzc)));
          float pre = ai[nt][i] + bi + rg * (ah[nt][i] + bc2);
          float ng = 2.f / (1.f + __expf(-2.f * pre)) - 1.f;
          out[(size_t)row * 128 + col] = (1.f - zg) * ng + zg * hpf[nt][i];
        }
      }
    }
  }
#undef GPASS
}

extern "C" void kernel_launch(void* const* d_in, const int* in_sizes, int n_in,
                              void* d_out, int out_size, void* d_ws,
                              size_t ws_size, hipStream_t stream) {
  const float* ns = (const float*)d_in[0];
  const float* ef = (const float*)d_in[1];
  const int* from_idx = (const int*)d_in[2];
  const int* to_idx = (const int*)d_in[3];
  const float* mW1 = (const float*)d_in[5];
  const float* mb1 = (const float*)d_in[6];
  const float* mW2 = (const float*)d_in[7];
  const float* mb2 = (const float*)d_in[8];
  const float* mW3 = (const float*)d_in[9];
  const float* mb3 = (const float*)d_in[10];
  const float* gW[3] = {(const float*)d_in[11], (const float*)d_in[15], (const float*)d_in[19]};
  const float* gU[3] = {(const float*)d_in[12], (const float*)d_in[16], (const float*)d_in[20]};
  const float* gb[3] = {(const float*)d_in[13], (const float*)d_in[17], (const float*)d_in[21]};
  const float* gc[3] = {(const float*)d_in[14], (const float*)d_in[18], (const float*)d_in[22]};

  const int N = in_sizes[0] / 128;
  const int E = in_sizes[1] / 128;

  char* base = (char*)d_ws;
  size_t cur = 0;
  auto alloc = [&](size_t bytes) {
    size_t p = cur;
    cur = (cur + bytes + 255) & ~(size_t)255;
    return (void*)(base + p);
  };
  float* aggf = (float*)alloc((size_t)N * 128 * 4);
  u16* Pa = (u16*)alloc((size_t)N * 128 * 2);
  u16* Pb = (u16*)alloc((size_t)N * 128 * 2);
  u16* Wt1 = (u16*)alloc(384 * 128 * 2);
  u16* Wt2 = (u16*)alloc(128 * 128 * 2);
  u16* Wt3 = (u16*)alloc(128 * 128 * 2);
  u16 *gWt[3], *gUt[3];
  for (int i = 0; i < 3; ++i) {
    gWt[i] = (u16*)alloc(384 * 128 * 2);
    gUt[i] = (u16*)alloc(384 * 128 * 2);
  }
  int* cnt = (int*)alloc((size_t)N * 4);
  int* off = (int*)alloc((size_t)(N + 1) * 4);
  int* cursor = (int*)alloc((size_t)N * 4);
  int* partial = (int*)alloc(256 * 4);
  int* pos0 = (int*)alloc((size_t)E * 4);
  int* pos1 = (int*)alloc((size_t)E * 4);
  u16* aggb = (u16*)alloc((size_t)N * 128 * 2);
  u16* msg = (u16*)alloc((size_t)2 * E * 128 * 2);
  bool csr_ok = (cur <= ws_size);

  {
    TransDesc td;
    const float* srcs[9] = {mW1, mW2, mW3, gW[0], gU[0], gW[1], gU[1], gW[2], gU[2]};
    u16* dsts[9] = {Wt1, Wt2, Wt3, gWt[0], gUt[0], gWt[1], gUt[1], gWt[2], gUt[2]};
    int Rs[9] = {384, 128, 128, 128, 128, 128, 128, 128, 128};
    int Cs[9] = {128, 128, 128, 384, 384, 384, 384, 384, 384};
    int acc = 0;
    for (int i = 0; i < 9; ++i) {
      td.src[i] = srcs[i];
      td.dst[i] = dsts[i];
      td.R[i] = Rs[i];
      td.C[i] = Cs[i];
      td.pre[i] = acc;
      acc += Rs[i] * Cs[i];
    }
    td.pre[9] = acc;
    transpose_all_kernel<<<(acc + 255) / 256, 256, 0, stream>>>(td);
  }

  node_partial_kernel<<<(N + 63) / 64, 256, 0, stream>>>(ns, Wt1, Pa, Pb, N);

  if (csr_ok) {
    hipMemsetAsync(cnt, 0, (size_t)N * 4, stream);
    count_kernel<<<(E + 255) / 256, 256, 0, stream>>>(from_idx, to_idx, cnt, E);
    int chunk = (N + 255) / 256;
    scan1_kernel<<<256, 256, 0, stream>>>(cnt, partial, N, chunk);
    scan2_kernel<<<1, 256, 0, stream>>>(partial, off, N);
    scan3_kernel<<<256, 256, 0, stream>>>(cnt, partial, off, cursor, N, chunk);
    pos_kernel<<<(E + 255) / 256, 256, 0, stream>>>(from_idx, to_idx, cursor,
                                                    pos0, pos1, E);
    int ntiles = (E + 31) / 32;
    int egrid = ntiles < 1280 ? ntiles : 1280;
    edge_slim_kernel<<<egrid, 256, 0, stream>>>(
        ef, from_idx, to_idx, Wt1, Wt2, Wt3, Pa, Pb, mb1, mb2, mb3, pos0, pos1,
        msg, E, ntiles);
    agg_csr_kernel<<<(N + 3) / 4, 256, 0, stream>>>(msg, off, aggf, N);
  } else {
    hipMemsetAsync(aggb, 0, (size_t)N * 128 * 2, stream);
    int ntiles = (E + 63) / 64;
    int egrid = ntiles < 512 ? ntiles : 512;
    edge_atomic_kernel<<<egrid, 512, 0, stream>>>(
        ef, from_idx, to_idx, Wt1, Wt2, Wt3, Pa, Pb, mb1, mb2, mb3, aggb, E,
        ntiles);
    bf16_to_f32_kernel<<<(N * 16 + 255) / 256, 256, 0, stream>>>(aggb, aggf, N * 16);
  }

  int gblocks = (N + 63) / 64;
  gru3_kernel<<<gblocks, 256, 0, stream>>>(
      ns, aggf, gWt[0], gUt[0], gWt[1], gUt[1], gWt[2], gUt[2], gb[0], gc[0],
      gb[1], gc[1], gb[2], gc[2], (float*)d_out, N);
}

// Round 8
// 648.851 us; speedup vs baseline: 3.0061x; 3.0061x over previous
//
#include <hip/hip_runtime.h>

typedef unsigned short u16;
typedef __attribute__((ext_vector_type(8))) short bf16x8;
typedef __attribute__((ext_vector_type(4))) float f32x4;

__device__ inline u16 f2bf(float f) {
  unsigned int u = __float_as_uint(f);
  u += 0x7fffu + ((u >> 16) & 1u);
  return (u16)(u >> 16);
}
__device__ inline float bf2f(u16 v) {
  return __uint_as_float((unsigned)v << 16);
}

__device__ inline uint4 pack8(float4 a, float4 b) {
  uint4 r;
  r.x = (unsigned)f2bf(a.x) | ((unsigned)f2bf(a.y) << 16);
  r.y = (unsigned)f2bf(a.z) | ((unsigned)f2bf(a.w) << 16);
  r.z = (unsigned)f2bf(b.x) | ((unsigned)f2bf(b.y) << 16);
  r.w = (unsigned)f2bf(b.z) | ((unsigned)f2bf(b.w) << 16);
  return r;
}

// ---- fused one-shot weight transpose: dst[c*R+r] = bf16(src[r*C+c]) ----
struct TransDesc {
  const float* src[9];
  u16* dst[9];
  int R[9];
  int C[9];
  int pre[10];
};

__global__ void transpose_all_kernel(TransDesc td) {
  int t = blockIdx.x * 256 + threadIdx.x;
  if (t >= td.pre[9]) return;
  int seg = 0;
  while (t >= td.pre[seg + 1]) ++seg;
  int local = t - td.pre[seg];
  int C = td.C[seg], R = td.R[seg];
  int r = local / C, c = local - r * C;
  td.dst[seg][(size_t)c * R + r] = f2bf(td.src[seg][local]);
}

// ---------------- CSR slot build ----------------
__global__ void count_kernel(const int* __restrict__ fi,
                             const int* __restrict__ ti,
                             int* __restrict__ cnt, int E) {
  int e = blockIdx.x * 256 + threadIdx.x;
  if (e < E) {
    atomicAdd(&cnt[ti[e]], 1);
    atomicAdd(&cnt[fi[e]], 1);
  }
}

__global__ void scan1_kernel(const int* __restrict__ cnt,
                             int* __restrict__ partial, int N, int chunk) {
  __shared__ int sdata[256];
  int b = blockIdx.x, t = threadIdx.x;
  int base = b * chunk;
  int sum = 0;
  for (int i = t; i < chunk; i += 256) {
    int idx = base + i;
    if (idx < N) sum += cnt[idx];
  }
  sdata[t] = sum;
  __syncthreads();
  for (int s2 = 128; s2 > 0; s2 >>= 1) {
    if (t < s2) sdata[t] += sdata[t + s2];
    __syncthreads();
  }
  if (t == 0) partial[b] = sdata[0];
}

__global__ void scan2_kernel(int* __restrict__ partial) {
  __shared__ int s[256];
  int t = threadIdx.x;
  int own = partial[t];
  s[t] = own;
  __syncthreads();
  for (int d2 = 1; d2 < 256; d2 <<= 1) {
    int v = (t >= d2) ? s[t - d2] : 0;
    __syncthreads();
    s[t] += v;
    __syncthreads();
  }
  partial[t] = s[t] - own;  // exclusive
}

__global__ void scan3_kernel(const int* __restrict__ cnt,
                             const int* __restrict__ partialEx,
                             int* __restrict__ cursor, int N, int chunk) {
  __shared__ int s[256];
  int b = blockIdx.x, t = threadIdx.x;
  int base = b * chunk;
  int own = (t < chunk && base + t < N) ? cnt[base + t] : 0;
  s[t] = own;
  __syncthreads();
  for (int d2 = 1; d2 < 256; d2 <<= 1) {
    int v = (t >= d2) ? s[t - d2] : 0;
    __syncthreads();
    s[t] += v;
    __syncthreads();
  }
  int ex = s[t] - own + partialEx[b];
  if (t < chunk && base + t < N) cursor[base + t] = ex;
}

// slot r (sorted by destination): nbr = gathered neighbor (Pa side),
// eid = edge, dest = destination node (Pb side + scatter target)
__global__ void slot_kernel(const int* __restrict__ fi,
                            const int* __restrict__ ti,
                            int* __restrict__ cursor, int* __restrict__ s_nbr,
                            int* __restrict__ s_eid, int* __restrict__ s_dest,
                            int E) {
  int e = blockIdx.x * 256 + threadIdx.x;
  if (e < E) {
    int f = fi[e], t2 = ti[e];
    int p0 = atomicAdd(&cursor[t2], 1);  // dir0: to ti, gather fi
    s_nbr[p0] = f;
    s_eid[p0] = e;
    s_dest[p0] = t2;
    int p1 = atomicAdd(&cursor[f], 1);   // dir1: to fi, gather ti
    s_nbr[p1] = t2;
    s_eid[p1] = e;
    s_dest[p1] = f;
  }
}

// ---- shared MFMA helpers (verified R1-R7) ----
__device__ inline void stage_w_rw(u16* sW, const u16* __restrict__ src,
                                  int roww, int colofs, int tid) {
  int n = tid >> 1, half = tid & 1;
  const u16* s = src + (size_t)n * roww + colofs + half * 64;
#pragma unroll
  for (int q = 0; q < 8; ++q) {
    uint4 v = *(const uint4*)(s + q * 8);
    int byte = n * 256 + ((half * 128 + q * 16) ^ ((n & 7) << 4));
    *(uint4*)((char*)sW + byte) = v;
  }
}

__device__ inline void mfma_pass(const u16* A, const u16* W, f32x4 acc[8],
                                 int w, int lane) {
  const int cA = lane & 15;
  const int ko = (lane >> 4) * 8;
  const int arow = 16 * w + cA;
#pragma unroll
  for (int kk = 0; kk < 4; ++kk) {
    int ka = (kk * 32 + ko) * 2;
    int sx = ka ^ ((cA & 7) << 4);
    bf16x8 a = *(const bf16x8*)((const char*)A + arow * 256 + sx);
#pragma unroll
    for (int nt = 0; nt < 8; ++nt) {
      bf16x8 bb = *(const bf16x8*)((const char*)W + (nt * 16 + cA) * 256 + sx);
      acc[nt] = __builtin_amdgcn_mfma_f32_16x16x32_bf16(a, bb, acc[nt], 0, 0, 0);
    }
  }
}

__device__ inline void write_h_lds(u16* sH, const f32x4 acc[8], int w,
                                   int lane) {
#pragma unroll
  for (int nt = 0; nt < 8; ++nt) {
    int col = nt * 16 + (lane & 15);
#pragma unroll
    for (int i = 0; i < 4; ++i) {
      int rr = 16 * w + ((lane >> 4) * 4) + i;
      *(u16*)((char*)sH + rr * 256 + ((col * 2) ^ ((rr & 7) << 4))) =
          f2bf(acc[nt][i]);
    }
  }
}

// Pa = bf16(ns @ W1a), Pb = bf16(ns @ W1b)
__global__ __launch_bounds__(256) void node_partial_kernel(
    const float* __restrict__ ns, const u16* __restrict__ Wt1,
    u16* __restrict__ Pa, u16* __restrict__ Pb, int N) {
  __shared__ u16 sA[64 * 128];
  __shared__ u16 sW[128 * 128];
  const int tid = threadIdx.x;
  const int lane = tid & 63;
  const int w = tid >> 6;
  const int r0 = blockIdx.x * 64;
  {
    int row = tid >> 2, seg = tid & 3;
    int rr = r0 + row;
    if (rr >= N) rr = N - 1;
    const float4* sx = (const float4*)(ns + (size_t)rr * 128 + seg * 32);
#pragma unroll
    for (int q = 0; q < 4; ++q) {
      int byte = row * 256 + ((seg * 64 + q * 16) ^ ((row & 7) << 4));
      *(uint4*)((char*)sA + byte) = pack8(sx[q * 2], sx[q * 2 + 1]);
    }
  }
  stage_w_rw(sW, Wt1, 384, 0, tid);
  __syncthreads();
  f32x4 accA[8] = {};
  mfma_pass(sA, sW, accA, w, lane);
  __syncthreads();
  stage_w_rw(sW, Wt1, 384, 128, tid);
  __syncthreads();
  f32x4 accB[8] = {};
  mfma_pass(sA, sW, accB, w, lane);
#pragma unroll
  for (int nt = 0; nt < 8; ++nt) {
    int col = nt * 16 + (lane & 15);
#pragma unroll
    for (int i = 0; i < 4; ++i) {
      int rr = 16 * w + ((lane >> 4) * 4) + i;
      int row = r0 + rr;
      if (row < N) {
        Pa[(size_t)row * 128 + col] = f2bf(accA[nt][i]);
        Pb[(size_t)row * 128 + col] = f2bf(accB[nt][i]);
      }
    }
  }
}

// EFm = bf16(ef @ W1c + b1)  — streaming GEMM (verified R6)
__global__ __launch_bounds__(256) void efgemm_kernel(
    const float* __restrict__ ef, const u16* __restrict__ Wt1,
    const float* __restrict__ b1, u16* __restrict__ EFm, int E) {
  __shared__ u16 sA[64 * 128];
  __shared__ u16 sW[128 * 128];
  const int tid = threadIdx.x;
  const int lane = tid & 63;
  const int w = tid >> 6;
  const int r0 = blockIdx.x * 64;
  {
    int row = tid >> 2, seg = tid & 3;
    int rr = r0 + row;
    if (rr >= E) rr = E - 1;
    const float4* sx = (const float4*)(ef + (size_t)rr * 128 + seg * 32);
#pragma unroll
    for (int q = 0; q < 4; ++q) {
      int byte = row * 256 + ((seg * 64 + q * 16) ^ ((row & 7) << 4));
      *(uint4*)((char*)sA + byte) = pack8(sx[q * 2], sx[q * 2 + 1]);
    }
  }
  stage_w_rw(sW, Wt1, 384, 256, tid);
  __syncthreads();
  f32x4 acc[8] = {};
  mfma_pass(sA, sW, acc, w, lane);
  __syncthreads();
#pragma unroll
  for (int nt = 0; nt < 8; ++nt) {
    int col = nt * 16 + (lane & 15);
    float bv = b1[col];
#pragma unroll
    for (int i = 0; i < 4; ++i) {
      int rr = 16 * w + ((lane >> 4) * 4) + i;
      *(u16*)((char*)sA + rr * 256 + ((col * 2) ^ ((rr & 7) << 4))) =
          f2bf(acc[nt][i] + bv);
    }
  }
  __syncthreads();
#pragma unroll
  for (int it = 0; it < 4; ++it) {
    int task = tid + (it << 8);
    int row = task >> 4, c8 = task & 15;
    int gr = r0 + row;
    if (gr < E) {
      uint4 v = *(const uint4*)((const char*)sA + row * 256 +
                                ((c8 << 4) ^ ((row & 7) << 4)));
      *(uint4*)(EFm + (size_t)gr * 128 + (c8 << 3)) = v;
    }
  }
}

// Destination-sorted edge MLP + in-tile segment reduction.
// Tile = 128 consecutive slots (dest-ordered). H1 = relu(EFm[eid] + Pa[nbr]
// + Pb[dest]); layers 2/3 via pinned W2/W3 frags (R5-verified phases); OUT
// reduced per dest-segment in LDS -> f32 atomicAdd into aggf.
__global__ __launch_bounds__(512, 2) void edge_csr_kernel(
    const u16* __restrict__ EFm, const int* __restrict__ s_nbr,
    const int* __restrict__ s_eid, const int* __restrict__ s_dest,
    const u16* __restrict__ Wt2, const u16* __restrict__ Wt3,
    const u16* __restrict__ Pa, const u16* __restrict__ Pb,
    const float* __restrict__ b2, const float* __restrict__ b3,
    float* __restrict__ aggf, int nslots, int ntiles) {
  __shared__ u16 sH[128 * 128];  // 32 KB
  __shared__ int sNbr[128];
  __shared__ int sEid[128];
  __shared__ int sDest[128];
  const int tid = threadIdx.x;
  const int lane = tid & 63;
  const int wv = tid >> 6;  // 0..7
  const int mw = wv >> 1;   // rows mw*32..+31
  const int nw = wv & 1;    // cols nw*64..+63
  const int l15 = lane & 15;
  const int lhi = lane >> 4;

  float b2f[4], b3f[4];
#pragma unroll
  for (int nt = 0; nt < 4; ++nt) {
    int col = (nw << 6) + (nt << 4) + l15;
    b2f[nt] = b2[col];
    b3f[nt] = b3[col];
  }
  bf16x8 w2f[4][4], w3f[4][4];
#pragma unroll
  for (int nt = 0; nt < 4; ++nt) {
    int c = (nw << 6) + (nt << 4) + l15;
#pragma unroll
    for (int kk = 0; kk < 4; ++kk) {
      w2f[nt][kk] = *(const bf16x8*)(Wt2 + (size_t)c * 128 + (kk << 5) + (lhi << 3));
      w3f[nt][kk] = *(const bf16x8*)(Wt3 + (size_t)c * 128 + (kk << 5) + (lhi << 3));
    }
  }
  __syncthreads();

  for (int t = blockIdx.x; t < ntiles; t += gridDim.x) {
    const int r0 = t << 7;  // 128 slots
    // P0: slot meta
    if (tid < 128) {
      int r = r0 + tid;
      int rc = r < nslots ? r : nslots - 1;
      sNbr[tid] = s_nbr[rc];
      sEid[tid] = s_eid[rc];
      sDest[tid] = (r < nslots) ? s_dest[rc] : -1;
    }
    __syncthreads();  // B0: meta ready
    // Phase C: H1 = relu(EFm[eid] + Pa[nbr] + Pb[dest]) -> sH
#pragma unroll
    for (int it = 0; it < 4; ++it) {
      int row = (tid >> 4) + (it << 5);  // 0..127
      int c8 = tid & 15;
      int nbr = sNbr[row], eid = sEid[row];
      int dst = sDest[row];
      if (dst < 0) dst = 0;  // safe dummy
      uint4 efv = *(const uint4*)(EFm + (size_t)eid * 128 + (c8 << 3));
      uint4 pav = *(const uint4*)(Pa + (size_t)nbr * 128 + (c8 << 3));
      uint4 pbv = *(const uint4*)(Pb + (size_t)dst * 128 + (c8 << 3));
      const u16* pe = (const u16*)&efv;
      const u16* pa = (const u16*)&pav;
      const u16* pb = (const u16*)&pbv;
      unsigned o[4];
#pragma unroll
      for (int j = 0; j < 4; ++j) {
        float v0 = fmaxf(bf2f(pe[2 * j]) + bf2f(pa[2 * j]) + bf2f(pb[2 * j]), 0.f);
        float v1 = fmaxf(bf2f(pe[2 * j + 1]) + bf2f(pa[2 * j + 1]) + bf2f(pb[2 * j + 1]), 0.f);
        o[j] = (unsigned)f2bf(v0) | ((unsigned)f2bf(v1) << 16);
      }
      *(uint4*)((char*)sH + row * 256 + ((c8 << 4) ^ ((row & 7) << 4))) = *(uint4*)o;
    }
    __syncthreads();  // B1: H1 ready
    // Phase D: acc2 = H1 @ W2
    bf16x8 hA[2][4];
#pragma unroll
    for (int m = 0; m < 2; ++m) {
      int ra = (mw << 5) + (m << 4) + l15;
#pragma unroll
      for (int kk = 0; kk < 4; ++kk) {
        int sx = ((kk << 6) + (lhi << 4)) ^ ((ra & 7) << 4);
        hA[m][kk] = *(const bf16x8*)((const char*)sH + ra * 256 + sx);
      }
    }
    f32x4 acc2[2][4] = {};
#pragma unroll
    for (int kk = 0; kk < 4; ++kk)
#pragma unroll
      for (int nt = 0; nt < 4; ++nt)
#pragma unroll
        for (int m = 0; m < 2; ++m)
          acc2[m][nt] = __builtin_amdgcn_mfma_f32_16x16x32_bf16(
              hA[m][kk], w2f[nt][kk], acc2[m][nt], 0, 0, 0);
    __syncthreads();  // B2: D reads done
    // Phase E: H2 = relu(acc2 + b2) -> sH
#pragma unroll
    for (int m = 0; m < 2; ++m) {
#pragma unroll
      for (int i = 0; i < 4; ++i) {
        int rl = (mw << 5) + (m << 4) + (lhi << 2) + i;
#pragma unroll
        for (int nt = 0; nt < 4; ++nt) {
          int col = (nw << 6) + (nt << 4) + l15;
          float v = fmaxf(acc2[m][nt][i] + b2f[nt], 0.f);
          *(u16*)((char*)sH + rl * 256 + ((col * 2) ^ ((rl & 7) << 4))) = f2bf(v);
        }
      }
    }
    __syncthreads();  // B3: H2 ready
    // Phase F: acc3 = H2 @ W3
#pragma unroll
    for (int m = 0; m < 2; ++m) {
      int ra = (mw << 5) + (m << 4) + l15;
#pragma unroll
      for (int kk = 0; kk < 4; ++kk) {
        int sx = ((kk << 6) + (lhi << 4)) ^ ((ra & 7) << 4);
        hA[m][kk] = *(const bf16x8*)((const char*)sH + ra * 256 + sx);
      }
    }
    f32x4 acc3[2][4] = {};
#pragma unroll
    for (int kk = 0; kk < 4; ++kk)
#pragma unroll
      for (int nt = 0; nt < 4; ++nt)
#pragma unroll
        for (int m = 0; m < 2; ++m)
          acc3[m][nt] = __builtin_amdgcn_mfma_f32_16x16x32_bf16(
              hA[m][kk], w3f[nt][kk], acc3[m][nt], 0, 0, 0);
    __syncthreads();  // B4: F reads done
    // OUT = acc3 + b3 -> sH (bf16)
#pragma unroll
    for (int m = 0; m < 2; ++m) {
#pragma unroll
      for (int i = 0; i < 4; ++i) {
        int rl = (mw << 5) + (m << 4) + (lhi << 2) + i;
#pragma unroll
        for (int nt = 0; nt < 4; ++nt) {
          int col = (nw << 6) + (nt << 4) + l15;
          *(u16*)((char*)sH + rl * 256 + ((col * 2) ^ ((rl & 7) << 4))) =
              f2bf(acc3[m][nt][i] + b3f[nt]);
        }
      }
    }
    __syncthreads();  // B5: OUT ready
    // Segment reduction: thread (col c, quarter q) scans 32 rows, flushes
    // one f32 atomic per dest-segment piece.
    {
      int c = tid & 127, q = tid >> 7;
      float s = 0.f;
      int prev = -1;
      int rbeg = q << 5;
#pragma unroll 4
      for (int rr = rbeg; rr < rbeg + 32; ++rr) {
        int d = sDest[rr];
        if (d != prev) {
          if (prev >= 0) unsafeAtomicAdd(&aggf[(size_t)prev * 128 + c], s);
          prev = d;
          s = 0.f;
        }
        if (d >= 0)
          s += bf2f(*(const u16*)((const char*)sH + rr * 256 +
                                  ((c * 2) ^ ((rr & 7) << 4))));
      }
      if (prev >= 0) unsafeAtomicAdd(&aggf[(size_t)prev * 128 + c], s);
    }
    __syncthreads();  // B6: sH/meta free for next tile
  }
}

// Fused 3-GRU chain (verified R5)
__global__ __launch_bounds__(256, 2) void gru3_kernel(
    const float* __restrict__ ns, const float* __restrict__ aggf,
    const u16* __restrict__ g0W, const u16* __restrict__ g0U,
    const u16* __restrict__ g1W, const u16* __restrict__ g1U,
    const u16* __restrict__ g2W, const u16* __restrict__ g2U,
    const float* __restrict__ b0, const float* __restrict__ c0,
    const float* __restrict__ b1, const float* __restrict__ c1,
    const float* __restrict__ b2, const float* __restrict__ c2,
    float* __restrict__ out, int N) {
  __shared__ u16 sX[64 * 128];
  __shared__ u16 sG[64 * 128];
  __shared__ u16 sW[128 * 128];
  const int tid = threadIdx.x;
  const int lane = tid & 63;
  const int w = tid >> 6;
  const int r0 = blockIdx.x * 64;
  {
    int row = tid >> 2, seg = tid & 3;
    int rr = r0 + row;
    if (rr >= N) rr = N - 1;
    const float4* sx = (const float4*)(ns + (size_t)rr * 128 + seg * 32);
    const float4* sh = (const float4*)(aggf + (size_t)rr * 128 + seg * 32);
#pragma unroll
    for (int q = 0; q < 4; ++q) {
      int byte = row * 256 + ((seg * 64 + q * 16) ^ ((row & 7) << 4));
      *(uint4*)((char*)sX + byte) = pack8(sx[q * 2], sx[q * 2 + 1]);
      *(uint4*)((char*)sG + byte) = pack8(sh[q * 2], sh[q * 2 + 1]);
    }
  }

  float hpf[8][4];

#define GPASS(SRC, ABUF, ACC)                       \
  __syncthreads();                                  \
  stage_w_rw(sW, (SRC), 128, 0, tid);               \
  __syncthreads();                                  \
  mfma_pass((ABUF), sW, (ACC), w, lane);

  {
    f32x4 ar[8] = {}, az[8] = {}, ai[8] = {}, ah[8] = {};
    GPASS(g0W + 0 * 16384, sX, ar)
    GPASS(g0U + 0 * 16384, sG, ar)
    GPASS(g0W + 1 * 16384, sX, az)
    GPASS(g0U + 1 * 16384, sG, az)
    GPASS(g0W + 2 * 16384, sX, ai)
    GPASS(g0U + 2 * 16384, sG, ah)
    f32x4 h1[8];
#pragma unroll
    for (int nt = 0; nt < 8; ++nt) {
      int col = nt * 16 + (lane & 15);
      float brc = b0[col] + c0[col];
      float bzc = b0[128 + col] + c0[128 + col];
      float bi = b0[256 + col];
      float bc2 = c0[256 + col];
#pragma unroll
      for (int i = 0; i < 4; ++i) {
        int rloc = 16 * w + ((lane >> 4) * 4) + i;
        int row = r0 + rloc;
        int rowc = row < N ? row : N - 1;
        float hf = aggf[(size_t)rowc * 128 + col];
        float rg = 1.f / (1.f + __expf(-(ar[nt][i] + brc)));
        float zg = 1.f / (1.f + __expf(-(az[nt][i] + bzc)));
        float pre = ai[nt][i] + bi + rg * (ah[nt][i] + bc2);
        float ng = 2.f / (1.f + __expf(-2.f * pre)) - 1.f;
        float hv = (1.f - zg) * ng + zg * hf;
        h1[nt][i] = hv;
        hpf[nt][i] = hv;
      }
    }
    write_h_lds(sX, h1, w, lane);
  }
  {
    f32x4 ar[8] = {}, az[8] = {}, ai[8] = {}, ah[8] = {};
    GPASS(g1W + 0 * 16384, sG, ar)
    GPASS(g1U + 0 * 16384, sX, ar)
    GPASS(g1W + 1 * 16384, sG, az)
    GPASS(g1U + 1 * 16384, sX, az)
    GPASS(g1W + 2 * 16384, sG, ai)
    GPASS(g1U + 2 * 16384, sX, ah)
    f32x4 h2[8];
#pragma unroll
    for (int nt = 0; nt < 8; ++nt) {
      int col = nt * 16 + (lane & 15);
      float brc = b1[col] + c1[col];
      float bzc = b1[128 + col] + c1[128 + col];
      float bi = b1[256 + col];
      float bc2 = c1[256 + col];
#pragma unroll
      for (int i = 0; i < 4; ++i) {
        float rg = 1.f / (1.f + __expf(-(ar[nt][i] + brc)));
        float zg = 1.f / (1.f + __expf(-(az[nt][i] + bzc)));
        float pre = ai[nt][i] + bi + rg * (ah[nt][i] + bc2);
        float ng = 2.f / (1.f + __expf(-2.f * pre)) - 1.f;
        float hv = (1.f - zg) * ng + zg * hpf[nt][i];
        h2[nt][i] = hv;
        hpf[nt][i] = hv;
      }
    }
    write_h_lds(sG, h2, w, lane);
  }
  {
    f32x4 ar[8] = {}, az[8] = {}, ai[8] = {}, ah[8] = {};
    GPASS(g2W + 0 * 16384, sX, ar)
    GPASS(g2U + 0 * 16384, sG, ar)
    GPASS(g2W + 1 * 16384, sX, az)
    GPASS(g2U + 1 * 16384, sG, az)
    GPASS(g2W + 2 * 16384, sX, ai)
    GPASS(g2U + 2 * 16384, sG, ah)
#pragma unroll
    for (int nt = 0; nt < 8; ++nt) {
      int col = nt * 16 + (lane & 15);
      float brc = b2[col] + c2[col];
      float bzc = b2[128 + col] + c2[128 + col];
      float bi = b2[256 + col];
      float bc2 = c2[256 + col];
#pragma unroll
      for (int i = 0; i < 4; ++i) {
        int rloc = 16 * w + ((lane >> 4) * 4) + i;
        int row = r0 + rloc;
        if (row < N) {
          float rg = 1.f / (1.f + __expf(-(ar[nt][i] + brc)));
          float zg = 1.f / (1.f + __expf(-(az[nt][i] + bzc)));
          float pre = ai[nt][i] + bi + rg * (ah[nt][i] + bc2);
          float ng = 2.f / (1.f + __expf(-2.f * pre)) - 1.f;
          out[(size_t)row * 128 + col] = (1.f - zg) * ng + zg * hpf[nt][i];
        }
      }
    }
  }
#undef GPASS
}

extern "C" void kernel_launch(void* const* d_in, const int* in_sizes, int n_in,
                              void* d_out, int out_size, void* d_ws,
                              size_t ws_size, hipStream_t stream) {
  const float* ns = (const float*)d_in[0];
  const float* ef = (const float*)d_in[1];
  const int* from_idx = (const int*)d_in[2];
  const int* to_idx = (const int*)d_in[3];
  const float* mW1 = (const float*)d_in[5];
  const float* mb1 = (const float*)d_in[6];
  const float* mW2 = (const float*)d_in[7];
  const float* mb2 = (const float*)d_in[8];
  const float* mW3 = (const float*)d_in[9];
  const float* mb3 = (const float*)d_in[10];
  const float* gW[3] = {(const float*)d_in[11], (const float*)d_in[15], (const float*)d_in[19]};
  const float* gU[3] = {(const float*)d_in[12], (const float*)d_in[16], (const float*)d_in[20]};
  const float* gb[3] = {(const float*)d_in[13], (const float*)d_in[17], (const float*)d_in[21]};
  const float* gc[3] = {(const float*)d_in[14], (const float*)d_in[18], (const float*)d_in[22]};

  const int N = in_sizes[0] / 128;
  const int E = in_sizes[1] / 128;
  const int nslots = 2 * E;

  char* base = (char*)d_ws;
  size_t cur = 0;
  auto alloc = [&](size_t bytes) {
    size_t p = cur;
    cur = (cur + bytes + 255) & ~(size_t)255;
    return (void*)(base + p);
  };
  float* aggf = (float*)alloc((size_t)N * 128 * 4);
  u16* Pa = (u16*)alloc((size_t)N * 128 * 2);
  u16* Pb = (u16*)alloc((size_t)N * 128 * 2);
  u16* Wt1 = (u16*)alloc(384 * 128 * 2);
  u16* Wt2 = (u16*)alloc(128 * 128 * 2);
  u16* Wt3 = (u16*)alloc(128 * 128 * 2);
  u16 *gWt[3], *gUt[3];
  for (int i = 0; i < 3; ++i) {
    gWt[i] = (u16*)alloc(384 * 128 * 2);
    gUt[i] = (u16*)alloc(384 * 128 * 2);
  }
  int* cnt = (int*)alloc((size_t)N * 4);
  int* cursor = (int*)alloc((size_t)N * 4);
  int* partial = (int*)alloc(256 * 4);
  int* s_nbr = (int*)alloc((size_t)nslots * 4);
  int* s_eid = (int*)alloc((size_t)nslots * 4);
  int* s_dest = (int*)alloc((size_t)nslots * 4);
  u16* EFm = (u16*)alloc((size_t)E * 128 * 2);
  (void)ws_size;  // ~193 MB total, well under all previously-fitting layouts

  {
    TransDesc td;
    const float* srcs[9] = {mW1, mW2, mW3, gW[0], gU[0], gW[1], gU[1], gW[2], gU[2]};
    u16* dsts[9] = {Wt1, Wt2, Wt3, gWt[0], gUt[0], gWt[1], gUt[1], gWt[2], gUt[2]};
    int Rs[9] = {384, 128, 128, 128, 128, 128, 128, 128, 128};
    int Cs[9] = {128, 128, 128, 384, 384, 384, 384, 384, 384};
    int acc = 0;
    for (int i = 0; i < 9; ++i) {
      td.src[i] = srcs[i];
      td.dst[i] = dsts[i];
      td.R[i] = Rs[i];
      td.C[i] = Cs[i];
      td.pre[i] = acc;
      acc += Rs[i] * Cs[i];
    }
    td.pre[9] = acc;
    transpose_all_kernel<<<(acc + 255) / 256, 256, 0, stream>>>(td);
  }

  node_partial_kernel<<<(N + 63) / 64, 256, 0, stream>>>(ns, Wt1, Pa, Pb, N);

  // CSR slot build
  hipMemsetAsync(cnt, 0, (size_t)N * 4, stream);
  count_kernel<<<(E + 255) / 256, 256, 0, stream>>>(from_idx, to_idx, cnt, E);
  int chunk = (N + 255) / 256;
  scan1_kernel<<<256, 256, 0, stream>>>(cnt, partial, N, chunk);
  scan2_kernel<<<1, 256, 0, stream>>>(partial);
  scan3_kernel<<<256, 256, 0, stream>>>(cnt, partial, cursor, N, chunk);
  slot_kernel<<<(E + 255) / 256, 256, 0, stream>>>(from_idx, to_idx, cursor,
                                                   s_nbr, s_eid, s_dest, E);

  // EF partial (streaming GEMM)
  efgemm_kernel<<<(E + 63) / 64, 256, 0, stream>>>(ef, Wt1, mb1, EFm, E);

  // destination-sorted edge MLP + fused aggregation
  hipMemsetAsync(aggf, 0, (size_t)N * 128 * 4, stream);
  int ntiles = (nslots + 127) / 128;
  int egrid = ntiles < 512 ? ntiles : 512;
  edge_csr_kernel<<<egrid, 512, 0, stream>>>(EFm, s_nbr, s_eid, s_dest, Wt2,
                                             Wt3, Pa, Pb, mb2, mb3, aggf,
                                             nslots, ntiles);

  int gblocks = (N + 63) / 64;
  gru3_kernel<<<gblocks, 256, 0, stream>>>(
      ns, aggf, gWt[0], gUt[0], gWt[1], gUt[1], gWt[2], gUt[2], gb[0], gc[0],
      gb[1], gc[1], gb[2], gc[2], (float*)d_out, N);
}

// Round 9
// 640.205 us; speedup vs baseline: 3.0467x; 1.0135x over previous
//
#include <hip/hip_runtime.h>

typedef unsigned short u16;
typedef __attribute__((ext_vector_type(8))) short bf16x8;
typedef __attribute__((ext_vector_type(4))) float f32x4;

__device__ inline u16 f2bf(float f) {
  unsigned int u = __float_as_uint(f);
  u += 0x7fffu + ((u >> 16) & 1u);
  return (u16)(u >> 16);
}
__device__ inline float bf2f(u16 v) {
  return __uint_as_float((unsigned)v << 16);
}

__device__ inline uint4 pack8(float4 a, float4 b) {
  uint4 r;
  r.x = (unsigned)f2bf(a.x) | ((unsigned)f2bf(a.y) << 16);
  r.y = (unsigned)f2bf(a.z) | ((unsigned)f2bf(a.w) << 16);
  r.z = (unsigned)f2bf(b.x) | ((unsigned)f2bf(b.y) << 16);
  r.w = (unsigned)f2bf(b.z) | ((unsigned)f2bf(b.w) << 16);
  return r;
}

// async global->LDS, 16B per lane; LDS dest = wave-uniform base + lane*16
__device__ inline void gload_lds16(const void* g, void* l) {
  __builtin_amdgcn_global_load_lds(
      (const __attribute__((address_space(1))) unsigned int*)g,
      (__attribute__((address_space(3))) unsigned int*)l, 16, 0, 0);
}

// ---- fused one-shot weight transpose: dst[c*R+r] = bf16(src[r*C+c]) ----
struct TransDesc {
  const float* src[9];
  u16* dst[9];
  int R[9];
  int C[9];
  int pre[10];
};

__global__ void transpose_all_kernel(TransDesc td) {
  int t = blockIdx.x * 256 + threadIdx.x;
  if (t >= td.pre[9]) return;
  int seg = 0;
  while (t >= td.pre[seg + 1]) ++seg;
  int local = t - td.pre[seg];
  int C = td.C[seg], R = td.R[seg];
  int r = local / C, c = local - r * C;
  td.dst[seg][(size_t)c * R + r] = f2bf(td.src[seg][local]);
}

// ---------------- CSR slot build ----------------
__global__ void count_kernel(const int* __restrict__ fi,
                             const int* __restrict__ ti,
                             int* __restrict__ cnt, int E) {
  int e = blockIdx.x * 256 + threadIdx.x;
  if (e < E) {
    atomicAdd(&cnt[ti[e]], 1);
    atomicAdd(&cnt[fi[e]], 1);
  }
}

__global__ void scan1_kernel(const int* __restrict__ cnt,
                             int* __restrict__ partial, int N, int chunk) {
  __shared__ int sdata[256];
  int b = blockIdx.x, t = threadIdx.x;
  int base = b * chunk;
  int sum = 0;
  for (int i = t; i < chunk; i += 256) {
    int idx = base + i;
    if (idx < N) sum += cnt[idx];
  }
  sdata[t] = sum;
  __syncthreads();
  for (int s2 = 128; s2 > 0; s2 >>= 1) {
    if (t < s2) sdata[t] += sdata[t + s2];
    __syncthreads();
  }
  if (t == 0) partial[b] = sdata[0];
}

__global__ void scan2_kernel(int* __restrict__ partial) {
  __shared__ int s[256];
  int t = threadIdx.x;
  int own = partial[t];
  s[t] = own;
  __syncthreads();
  for (int d2 = 1; d2 < 256; d2 <<= 1) {
    int v = (t >= d2) ? s[t - d2] : 0;
    __syncthreads();
    s[t] += v;
    __syncthreads();
  }
  partial[t] = s[t] - own;  // exclusive
}

__global__ void scan3_kernel(const int* __restrict__ cnt,
                             const int* __restrict__ partialEx,
                             int* __restrict__ cursor, int N, int chunk) {
  __shared__ int s[256];
  int b = blockIdx.x, t = threadIdx.x;
  int base = b * chunk;
  int own = (t < chunk && base + t < N) ? cnt[base + t] : 0;
  s[t] = own;
  __syncthreads();
  for (int d2 = 1; d2 < 256; d2 <<= 1) {
    int v = (t >= d2) ? s[t - d2] : 0;
    __syncthreads();
    s[t] += v;
    __syncthreads();
  }
  int ex = s[t] - own + partialEx[b];
  if (t < chunk && base + t < N) cursor[base + t] = ex;
}

__global__ void slot_kernel(const int* __restrict__ fi,
                            const int* __restrict__ ti,
                            int* __restrict__ cursor, int* __restrict__ s_nbr,
                            int* __restrict__ s_eid, int* __restrict__ s_dest,
                            int E) {
  int e = blockIdx.x * 256 + threadIdx.x;
  if (e < E) {
    int f = fi[e], t2 = ti[e];
    int p0 = atomicAdd(&cursor[t2], 1);
    s_nbr[p0] = f;
    s_eid[p0] = e;
    s_dest[p0] = t2;
    int p1 = atomicAdd(&cursor[f], 1);
    s_nbr[p1] = t2;
    s_eid[p1] = e;
    s_dest[p1] = f;
  }
}

// ---- shared MFMA helpers (verified R1-R8) ----
__device__ inline void stage_w_rw(u16* sW, const u16* __restrict__ src,
                                  int roww, int colofs, int tid) {
  int n = tid >> 1, half = tid & 1;
  const u16* s = src + (size_t)n * roww + colofs + half * 64;
#pragma unroll
  for (int q = 0; q < 8; ++q) {
    uint4 v = *(const uint4*)(s + q * 8);
    int byte = n * 256 + ((half * 128 + q * 16) ^ ((n & 7) << 4));
    *(uint4*)((char*)sW + byte) = v;
  }
}

__device__ inline void stage_w_512(u16* sW, const u16* __restrict__ src,
                                   int roww, int colofs, int tid) {
  int n = tid >> 2, quarter = tid & 3;
  const u16* s = src + (size_t)n * roww + colofs + quarter * 32;
#pragma unroll
  for (int q = 0; q < 4; ++q) {
    uint4 v = *(const uint4*)(s + q * 8);
    int byte = n * 256 + ((quarter * 64 + q * 16) ^ ((n & 7) << 4));
    *(uint4*)((char*)sW + byte) = v;
  }
}

__device__ inline void mfma_pass(const u16* A, const u16* W, f32x4 acc[8],
                                 int w, int lane) {
  const int cA = lane & 15;
  const int ko = (lane >> 4) * 8;
  const int arow = 16 * w + cA;
#pragma unroll
  for (int kk = 0; kk < 4; ++kk) {
    int ka = (kk * 32 + ko) * 2;
    int sx = ka ^ ((cA & 7) << 4);
    bf16x8 a = *(const bf16x8*)((const char*)A + arow * 256 + sx);
#pragma unroll
    for (int nt = 0; nt < 8; ++nt) {
      bf16x8 bb = *(const bf16x8*)((const char*)W + (nt * 16 + cA) * 256 + sx);
      acc[nt] = __builtin_amdgcn_mfma_f32_16x16x32_bf16(a, bb, acc[nt], 0, 0, 0);
    }
  }
}

__device__ inline void write_h_lds(u16* sH, const f32x4 acc[8], int w,
                                   int lane) {
#pragma unroll
  for (int nt = 0; nt < 8; ++nt) {
    int col = nt * 16 + (lane & 15);
#pragma unroll
    for (int i = 0; i < 4; ++i) {
      int rr = 16 * w + ((lane >> 4) * 4) + i;
      *(u16*)((char*)sH + rr * 256 + ((col * 2) ^ ((rr & 7) << 4))) =
          f2bf(acc[nt][i]);
    }
  }
}

// Pa = bf16(ns @ W1a), Pb = bf16(ns @ W1b)
__global__ __launch_bounds__(256) void node_partial_kernel(
    const float* __restrict__ ns, const u16* __restrict__ Wt1,
    u16* __restrict__ Pa, u16* __restrict__ Pb, int N) {
  __shared__ u16 sA[64 * 128];
  __shared__ u16 sW[128 * 128];
  const int tid = threadIdx.x;
  const int lane = tid & 63;
  const int w = tid >> 6;
  const int r0 = blockIdx.x * 64;
  {
    int row = tid >> 2, seg = tid & 3;
    int rr = r0 + row;
    if (rr >= N) rr = N - 1;
    const float4* sx = (const float4*)(ns + (size_t)rr * 128 + seg * 32);
#pragma unroll
    for (int q = 0; q < 4; ++q) {
      int byte = row * 256 + ((seg * 64 + q * 16) ^ ((row & 7) << 4));
      *(uint4*)((char*)sA + byte) = pack8(sx[q * 2], sx[q * 2 + 1]);
    }
  }
  stage_w_rw(sW, Wt1, 384, 0, tid);
  __syncthreads();
  f32x4 accA[8] = {};
  mfma_pass(sA, sW, accA, w, lane);
  __syncthreads();
  stage_w_rw(sW, Wt1, 384, 128, tid);
  __syncthreads();
  f32x4 accB[8] = {};
  mfma_pass(sA, sW, accB, w, lane);
#pragma unroll
  for (int nt = 0; nt < 8; ++nt) {
    int col = nt * 16 + (lane & 15);
#pragma unroll
    for (int i = 0; i < 4; ++i) {
      int rr = 16 * w + ((lane >> 4) * 4) + i;
      int row = r0 + rr;
      if (row < N) {
        Pa[(size_t)row * 128 + col] = f2bf(accA[nt][i]);
        Pb[(size_t)row * 128 + col] = f2bf(accB[nt][i]);
      }
    }
  }
}

// EFm = bf16(ef @ W1c + b1) — streaming GEMM, 128 rows / 512 threads
__global__ __launch_bounds__(512) void efgemm_kernel(
    const float* __restrict__ ef, const u16* __restrict__ Wt1,
    const float* __restrict__ b1, u16* __restrict__ EFm, int E) {
  __shared__ u16 sA[128 * 128];
  __shared__ u16 sW[128 * 128];
  const int tid = threadIdx.x;
  const int lane = tid & 63;
  const int w = tid >> 6;  // 0..7
  const int r0 = blockIdx.x * 128;
  {
    int row = tid >> 2, seg = tid & 3;
    int rr = r0 + row;
    if (rr >= E) rr = E - 1;
    const float4* sx = (const float4*)(ef + (size_t)rr * 128 + seg * 32);
#pragma unroll
    for (int q = 0; q < 4; ++q) {
      int byte = row * 256 + ((seg * 64 + q * 16) ^ ((row & 7) << 4));
      *(uint4*)((char*)sA + byte) = pack8(sx[q * 2], sx[q * 2 + 1]);
    }
  }
  stage_w_512(sW, Wt1, 384, 256, tid);
  __syncthreads();
  f32x4 acc[8] = {};
  mfma_pass(sA, sW, acc, w, lane);
  __syncthreads();  // all reads of sA done before overwrite
#pragma unroll
  for (int nt = 0; nt < 8; ++nt) {
    int col = nt * 16 + (lane & 15);
    float bv = b1[col];
#pragma unroll
    for (int i = 0; i < 4; ++i) {
      int rr = 16 * w + ((lane >> 4) * 4) + i;
      *(u16*)((char*)sA + rr * 256 + ((col * 2) ^ ((rr & 7) << 4))) =
          f2bf(acc[nt][i] + bv);
    }
  }
  __syncthreads();
#pragma unroll
  for (int it = 0; it < 4; ++it) {
    int task = tid + (it << 9);
    int row = task >> 4, c8 = task & 15;
    int gr = r0 + row;
    if (gr < E) {
      uint4 v = *(const uint4*)((const char*)sA + row * 256 +
                                ((c8 << 4) ^ ((row & 7) << 4)));
      *(uint4*)(EFm + (size_t)gr * 128 + (c8 << 3)) = v;
    }
  }
}

// Destination-sorted edge MLP with async LDS prefetch of next tile's gathers.
__global__ __launch_bounds__(512, 2) void edge_csr_kernel(
    const u16* __restrict__ EFm, const int* __restrict__ s_nbr,
    const int* __restrict__ s_eid, const int* __restrict__ s_dest,
    const u16* __restrict__ Wt2, const u16* __restrict__ Wt3,
    const u16* __restrict__ Pa, const u16* __restrict__ Pb,
    const float* __restrict__ b2, const float* __restrict__ b3,
    float* __restrict__ aggf, int nslots, int ntiles) {
  __shared__ u16 sH[128 * 128];      // 32 KB (swizzled H buffer)
  __shared__ u16 sPreEF[128 * 128];  // 32 KB (linear prefetch: EFm rows)
  __shared__ u16 sPrePA[128 * 128];  // 32 KB (Pa rows)
  __shared__ u16 sPrePB[128 * 128];  // 32 KB (Pb rows)
  __shared__ int sDest[128];
  const int tid = threadIdx.x;
  const int lane = tid & 63;
  const int wv = tid >> 6;  // 0..7
  const int mw = wv >> 1;   // rows mw*32..+31
  const int nw = wv & 1;    // cols nw*64..+63
  const int l15 = lane & 15;
  const int lhi = lane >> 4;
  const int c8 = tid & 15;
  const int wbase = (tid >> 6) << 10;  // byte base of this wave's lds slice

  float b2f[4], b3f[4];
#pragma unroll
  for (int nt = 0; nt < 4; ++nt) {
    int col = (nw << 6) + (nt << 4) + l15;
    b2f[nt] = b2[col];
    b3f[nt] = b3[col];
  }
  bf16x8 w2f[4][4], w3f[4][4];
#pragma unroll
  for (int nt = 0; nt < 4; ++nt) {
    int c = (nw << 6) + (nt << 4) + l15;
#pragma unroll
    for (int kk = 0; kk < 4; ++kk) {
      w2f[nt][kk] = *(const bf16x8*)(Wt2 + (size_t)c * 128 + (kk << 5) + (lhi << 3));
      w3f[nt][kk] = *(const bf16x8*)(Wt3 + (size_t)c * 128 + (kk << 5) + (lhi << 3));
    }
  }

  int nbr4[4], eid4[4], dst4[4];
  auto load_meta = [&](int tt) {
#pragma unroll
    for (int it = 0; it < 4; ++it) {
      int r = (tt << 7) + (tid >> 4) + (it << 5);
      int rc = r < nslots ? r : nslots - 1;
      nbr4[it] = s_nbr[rc];
      eid4[it] = s_eid[rc];
      dst4[it] = (r < nslots) ? s_dest[rc] : -1;
    }
  };
  auto issue_gathers = [&]() {
#pragma unroll
    for (int it = 0; it < 4; ++it) {
      int dd = dst4[it] < 0 ? 0 : dst4[it];
      int off = wbase + (it << 13);
      gload_lds16(EFm + (size_t)eid4[it] * 128 + (c8 << 3), (char*)sPreEF + off);
      gload_lds16(Pa + (size_t)nbr4[it] * 128 + (c8 << 3), (char*)sPrePA + off);
      gload_lds16(Pb + (size_t)dd * 128 + (c8 << 3), (char*)sPrePB + off);
    }
  };
  auto write_dest = [&]() {
    if ((tid & 15) == 0) {
#pragma unroll
      for (int it = 0; it < 4; ++it) sDest[(tid >> 4) + (it << 5)] = dst4[it];
    }
  };

  // prologue: prefetch first tile
  int t = blockIdx.x;
  if (t < ntiles) {
    load_meta(t);
    issue_gathers();
    write_dest();
  }
  __syncthreads();  // gathers drained + sDest visible

  for (; t < ntiles; t += gridDim.x) {
    const int tn = t + gridDim.x;
    const bool has_next = tn < ntiles;
    if (has_next) load_meta(tn);  // meta loads in flight under phase C
    // Phase C: H1 = relu(EF + Pa + Pb) from prefetched LDS -> sH (swizzled)
#pragma unroll
    for (int it = 0; it < 4; ++it) {
      int row = (tid >> 4) + (it << 5);
      int boff = row * 256 + (c8 << 4);
      uint4 efv = *(const uint4*)((const char*)sPreEF + boff);
      uint4 pav = *(const uint4*)((const char*)sPrePA + boff);
      uint4 pbv = *(const uint4*)((const char*)sPrePB + boff);
      const u16* pe = (const u16*)&efv;
      const u16* pa = (const u16*)&pav;
      const u16* pb = (const u16*)&pbv;
      unsigned o[4];
#pragma unroll
      for (int j = 0; j < 4; ++j) {
        float v0 = fmaxf(bf2f(pe[2 * j]) + bf2f(pa[2 * j]) + bf2f(pb[2 * j]), 0.f);
        float v1 = fmaxf(bf2f(pe[2 * j + 1]) + bf2f(pa[2 * j + 1]) + bf2f(pb[2 * j + 1]), 0.f);
        o[j] = (unsigned)f2bf(v0) | ((unsigned)f2bf(v1) << 16);
      }
      *(uint4*)((char*)sH + row * 256 + ((c8 << 4) ^ ((row & 7) << 4))) = *(uint4*)o;
    }
    __syncthreads();  // B1: H1 ready; sPre free
    if (has_next) issue_gathers();  // async into sPre, hides under D/E/F
    // Phase D: acc = H1 @ W2
    bf16x8 hA[2][4];
#pragma unroll
    for (int m = 0; m < 2; ++m) {
      int ra = (mw << 5) + (m << 4) + l15;
#pragma unroll
      for (int kk = 0; kk < 4; ++kk) {
        int sx = ((kk << 6) + (lhi << 4)) ^ ((ra & 7) << 4);
        hA[m][kk] = *(const bf16x8*)((const char*)sH + ra * 256 + sx);
      }
    }
    f32x4 acc[2][4] = {};
#pragma unroll
    for (int kk = 0; kk < 4; ++kk)
#pragma unroll
      for (int nt = 0; nt < 4; ++nt)
#pragma unroll
        for (int m = 0; m < 2; ++m)
          acc[m][nt] = __builtin_amdgcn_mfma_f32_16x16x32_bf16(
              hA[m][kk], w2f[nt][kk], acc[m][nt], 0, 0, 0);
    __syncthreads();  // B2: D reads done
    // Phase E: H2 = relu(acc + b2) -> sH; re-zero acc for layer 3
#pragma unroll
    for (int m = 0; m < 2; ++m) {
#pragma unroll
      for (int i = 0; i < 4; ++i) {
        int rl = (mw << 5) + (m << 4) + (lhi << 2) + i;
#pragma unroll
        for (int nt = 0; nt < 4; ++nt) {
          int col = (nw << 6) + (nt << 4) + l15;
          float v = fmaxf(acc[m][nt][i] + b2f[nt], 0.f);
          *(u16*)((char*)sH + rl * 256 + ((col * 2) ^ ((rl & 7) << 4))) = f2bf(v);
          acc[m][nt][i] = 0.f;
        }
      }
    }
    __syncthreads();  // B3: H2 ready
    // Phase F: acc = H2 @ W3
#pragma unroll
    for (int m = 0; m < 2; ++m) {
      int ra = (mw << 5) + (m << 4) + l15;
#pragma unroll
      for (int kk = 0; kk < 4; ++kk) {
        int sx = ((kk << 6) + (lhi << 4)) ^ ((ra & 7) << 4);
        hA[m][kk] = *(const bf16x8*)((const char*)sH + ra * 256 + sx);
      }
    }
#pragma unroll
    for (int kk = 0; kk < 4; ++kk)
#pragma unroll
      for (int nt = 0; nt < 4; ++nt)
#pragma unroll
        for (int m = 0; m < 2; ++m)
          acc[m][nt] = __builtin_amdgcn_mfma_f32_16x16x32_bf16(
              hA[m][kk], w3f[nt][kk], acc[m][nt], 0, 0, 0);
    __syncthreads();  // B4: F reads done
    // OUT = acc + b3 -> sH (bf16)
#pragma unroll
    for (int m = 0; m < 2; ++m) {
#pragma unroll
      for (int i = 0; i < 4; ++i) {
        int rl = (mw << 5) + (m << 4) + (lhi << 2) + i;
#pragma unroll
        for (int nt = 0; nt < 4; ++nt) {
          int col = (nw << 6) + (nt << 4) + l15;
          *(u16*)((char*)sH + rl * 256 + ((col * 2) ^ ((rl & 7) << 4))) =
              f2bf(acc[m][nt][i] + b3f[nt]);
        }
      }
    }
    __syncthreads();  // B5: OUT ready
    // Segment reduction (dest-sorted): thread (col c, quarter q) scans 32 rows
    {
      int c = tid & 127, q = tid >> 7;
      float s = 0.f;
      int prev = -1;
      int rbeg = q << 5;
#pragma unroll 4
      for (int rr = rbeg; rr < rbeg + 32; ++rr) {
        int d = sDest[rr];
        if (d != prev) {
          if (prev >= 0) unsafeAtomicAdd(&aggf[(size_t)prev * 128 + c], s);
          prev = d;
          s = 0.f;
        }
        if (d >= 0)
          s += bf2f(*(const u16*)((const char*)sH + rr * 256 +
                                  ((c * 2) ^ ((rr & 7) << 4))));
      }
      if (prev >= 0) unsafeAtomicAdd(&aggf[(size_t)prev * 128 + c], s);
    }
    __syncthreads();  // B6: sH + sDest free
    if (has_next) write_dest();  // safe: all scans done
  }
}

// Fused 3-GRU chain (verified R5)
__global__ __launch_bounds__(256, 2) void gru3_kernel(
    const float* __restrict__ ns, const float* __restrict__ aggf,
    const u16* __restrict__ g0W, const u16* __restrict__ g0U,
    const u16* __restrict__ g1W, const u16* __restrict__ g1U,
    const u16* __restrict__ g2W, const u16* __restrict__ g2U,
    const float* __restrict__ b0, const float* __restrict__ c0,
    const float* __restrict__ b1, const float* __restrict__ c1,
    const float* __restrict__ b2, const float* __restrict__ c2,
    float* __restrict__ out, int N) {
  __shared__ u16 sX[64 * 128];
  __shared__ u16 sG[64 * 128];
  __shared__ u16 sW[128 * 128];
  const int tid = threadIdx.x;
  const int lane = tid & 63;
  const int w = tid >> 6;
  const int r0 = blockIdx.x * 64;
  {
    int row = tid >> 2, seg = tid & 3;
    int rr = r0 + row;
    if (rr >= N) rr = N - 1;
    const float4* sx = (const float4*)(ns + (size_t)rr * 128 + seg * 32);
    const float4* sh = (const float4*)(aggf + (size_t)rr * 128 + seg * 32);
#pragma unroll
    for (int q = 0; q < 4; ++q) {
      int byte = row * 256 + ((seg * 64 + q * 16) ^ ((row & 7) << 4));
      *(uint4*)((char*)sX + byte) = pack8(sx[q * 2], sx[q * 2 + 1]);
      *(uint4*)((char*)sG + byte) = pack8(sh[q * 2], sh[q * 2 + 1]);
    }
  }

  float hpf[8][4];

#define GPASS(SRC, ABUF, ACC)                       \
  __syncthreads();                                  \
  stage_w_rw(sW, (SRC), 128, 0, tid);               \
  __syncthreads();                                  \
  mfma_pass((ABUF), sW, (ACC), w, lane);

  {
    f32x4 ar[8] = {}, az[8] = {}, ai[8] = {}, ah[8] = {};
    GPASS(g0W + 0 * 16384, sX, ar)
    GPASS(g0U + 0 * 16384, sG, ar)
    GPASS(g0W + 1 * 16384, sX, az)
    GPASS(g0U + 1 * 16384, sG, az)
    GPASS(g0W + 2 * 16384, sX, ai)
    GPASS(g0U + 2 * 16384, sG, ah)
    f32x4 h1[8];
#pragma unroll
    for (int nt = 0; nt < 8; ++nt) {
      int col = nt * 16 + (lane & 15);
      float brc = b0[col] + c0[col];
      float bzc = b0[128 + col] + c0[128 + col];
      float bi = b0[256 + col];
      float bc2 = c0[256 + col];
#pragma unroll
      for (int i = 0; i < 4; ++i) {
        int rloc = 16 * w + ((lane >> 4) * 4) + i;
        int row = r0 + rloc;
        int rowc = row < N ? row : N - 1;
        float hf = aggf[(size_t)rowc * 128 + col];
        float rg = 1.f / (1.f + __expf(-(ar[nt][i] + brc)));
        float zg = 1.f / (1.f + __expf(-(az[nt][i] + bzc)));
        float pre = ai[nt][i] + bi + rg * (ah[nt][i] + bc2);
        float ng = 2.f / (1.f + __expf(-2.f * pre)) - 1.f;
        float hv = (1.f - zg) * ng + zg * hf;
        h1[nt][i] = hv;
        hpf[nt][i] = hv;
      }
    }
    write_h_lds(sX, h1, w, lane);
  }
  {
    f32x4 ar[8] = {}, az[8] = {}, ai[8] = {}, ah[8] = {};
    GPASS(g1W + 0 * 16384, sG, ar)
    GPASS(g1U + 0 * 16384, sX, ar)
    GPASS(g1W + 1 * 16384, sG, az)
    GPASS(g1U + 1 * 16384, sX, az)
    GPASS(g1W + 2 * 16384, sG, ai)
    GPASS(g1U + 2 * 16384, sX, ah)
    f32x4 h2[8];
#pragma unroll
    for (int nt = 0; nt < 8; ++nt) {
      int col = nt * 16 + (lane & 15);
      float brc = b1[col] + c1[col];
      float bzc = b1[128 + col] + c1[128 + col];
      float bi = b1[256 + col];
      float bc2 = c1[256 + col];
#pragma unroll
      for (int i = 0; i < 4; ++i) {
        float rg = 1.f / (1.f + __expf(-(ar[nt][i] + brc)));
        float zg = 1.f / (1.f + __expf(-(az[nt][i] + bzc)));
        float pre = ai[nt][i] + bi + rg * (ah[nt][i] + bc2);
        float ng = 2.f / (1.f + __expf(-2.f * pre)) - 1.f;
        float hv = (1.f - zg) * ng + zg * hpf[nt][i];
        h2[nt][i] = hv;
        hpf[nt][i] = hv;
      }
    }
    write_h_lds(sG, h2, w, lane);
  }
  {
    f32x4 ar[8] = {}, az[8] = {}, ai[8] = {}, ah[8] = {};
    GPASS(g2W + 0 * 16384, sX, ar)
    GPASS(g2U + 0 * 16384, sG, ar)
    GPASS(g2W + 1 * 16384, sX, az)
    GPASS(g2U + 1 * 16384, sG, az)
    GPASS(g2W + 2 * 16384, sX, ai)
    GPASS(g2U + 2 * 16384, sG, ah)
#pragma unroll
    for (int nt = 0; nt < 8; ++nt) {
      int col = nt * 16 + (lane & 15);
      float brc = b2[col] + c2[col];
      float bzc = b2[128 + col] + c2[128 + col];
      float bi = b2[256 + col];
      float bc2 = c2[256 + col];
#pragma unroll
      for (int i = 0; i < 4; ++i) {
        int rloc = 16 * w + ((lane >> 4) * 4) + i;
        int row = r0 + rloc;
        if (row < N) {
          float rg = 1.f / (1.f + __expf(-(ar[nt][i] + brc)));
          float zg = 1.f / (1.f + __expf(-(az[nt][i] + bzc)));
          float pre = ai[nt][i] + bi + rg * (ah[nt][i] + bc2);
          float ng = 2.f / (1.f + __expf(-2.f * pre)) - 1.f;
          out[(size_t)row * 128 + col] = (1.f - zg) * ng + zg * hpf[nt][i];
        }
      }
    }
  }
#undef GPASS
}

extern "C" void kernel_launch(void* const* d_in, const int* in_sizes, int n_in,
                              void* d_out, int out_size, void* d_ws,
                              size_t ws_size, hipStream_t stream) {
  const float* ns = (const float*)d_in[0];
  const float* ef = (const float*)d_in[1];
  const int* from_idx = (const int*)d_in[2];
  const int* to_idx = (const int*)d_in[3];
  const float* mW1 = (const float*)d_in[5];
  const float* mb1 = (const float*)d_in[6];
  const float* mW2 = (const float*)d_in[7];
  const float* mb2 = (const float*)d_in[8];
  const float* mW3 = (const float*)d_in[9];
  const float* mb3 = (const float*)d_in[10];
  const float* gW[3] = {(const float*)d_in[11], (const float*)d_in[15], (const float*)d_in[19]};
  const float* gU[3] = {(const float*)d_in[12], (const float*)d_in[16], (const float*)d_in[20]};
  const float* gb[3] = {(const float*)d_in[13], (const float*)d_in[17], (const float*)d_in[21]};
  const float* gc[3] = {(const float*)d_in[14], (const float*)d_in[18], (const float*)d_in[22]};

  const int N = in_sizes[0] / 128;
  const int E = in_sizes[1] / 128;
  const int nslots = 2 * E;

  char* base = (char*)d_ws;
  size_t cur = 0;
  auto alloc = [&](size_t bytes) {
    size_t p = cur;
    cur = (cur + bytes + 255) & ~(size_t)255;
    return (void*)(base + p);
  };
  float* aggf = (float*)alloc((size_t)N * 128 * 4);
  u16* Pa = (u16*)alloc((size_t)N * 128 * 2);
  u16* Pb = (u16*)alloc((size_t)N * 128 * 2);
  u16* Wt1 = (u16*)alloc(384 * 128 * 2);
  u16* Wt2 = (u16*)alloc(128 * 128 * 2);
  u16* Wt3 = (u16*)alloc(128 * 128 * 2);
  u16 *gWt[3], *gUt[3];
  for (int i = 0; i < 3; ++i) {
    gWt[i] = (u16*)alloc(384 * 128 * 2);
    gUt[i] = (u16*)alloc(384 * 128 * 2);
  }
  int* cnt = (int*)alloc((size_t)N * 4);
  int* cursor = (int*)alloc((size_t)N * 4);
  int* partial = (int*)alloc(256 * 4);
  int* s_nbr = (int*)alloc((size_t)nslots * 4);
  int* s_eid = (int*)alloc((size_t)nslots * 4);
  int* s_dest = (int*)alloc((size_t)nslots * 4);
  u16* EFm = (u16*)alloc((size_t)E * 128 * 2);
  (void)ws_size;  // ~193 MB total

  {
    TransDesc td;
    const float* srcs[9] = {mW1, mW2, mW3, gW[0], gU[0], gW[1], gU[1], gW[2], gU[2]};
    u16* dsts[9] = {Wt1, Wt2, Wt3, gWt[0], gUt[0], gWt[1], gUt[1], gWt[2], gUt[2]};
    int Rs[9] = {384, 128, 128, 128, 128, 128, 128, 128, 128};
    int Cs[9] = {128, 128, 128, 384, 384, 384, 384, 384, 384};
    int acc = 0;
    for (int i = 0; i < 9; ++i) {
      td.src[i] = srcs[i];
      td.dst[i] = dsts[i];
      td.R[i] = Rs[i];
      td.C[i] = Cs[i];
      td.pre[i] = acc;
      acc += Rs[i] * Cs[i];
    }
    td.pre[9] = acc;
    transpose_all_kernel<<<(acc + 255) / 256, 256, 0, stream>>>(td);
  }

  node_partial_kernel<<<(N + 63) / 64, 256, 0, stream>>>(ns, Wt1, Pa, Pb, N);

  // CSR slot build
  hipMemsetAsync(cnt, 0, (size_t)N * 4, stream);
  count_kernel<<<(E + 255) / 256, 256, 0, stream>>>(from_idx, to_idx, cnt, E);
  int chunk = (N + 255) / 256;
  scan1_kernel<<<256, 256, 0, stream>>>(cnt, partial, N, chunk);
  scan2_kernel<<<1, 256, 0, stream>>>(partial);
  scan3_kernel<<<256, 256, 0, stream>>>(cnt, partial, cursor, N, chunk);
  slot_kernel<<<(E + 255) / 256, 256, 0, stream>>>(from_idx, to_idx, cursor,
                                                   s_nbr, s_eid, s_dest, E);

  // EF partial (streaming GEMM, 128-row tiles)
  efgemm_kernel<<<(E + 127) / 128, 512, 0, stream>>>(ef, Wt1, mb1, EFm, E);

  // destination-sorted edge MLP + fused aggregation (prefetched)
  hipMemsetAsync(aggf, 0, (size_t)N * 128 * 4, stream);
  int ntiles = (nslots + 127) / 128;
  int egrid = ntiles < 256 ? ntiles : 256;
  edge_csr_kernel<<<egrid, 512, 0, stream>>>(EFm, s_nbr, s_eid, s_dest, Wt2,
                                             Wt3, Pa, Pb, mb2, mb3, aggf,
                                             nslots, ntiles);

  int gblocks = (N + 63) / 64;
  gru3_kernel<<<gblocks, 256, 0, stream>>>(
      ns, aggf, gWt[0], gUt[0], gWt[1], gUt[1], gWt[2], gUt[2], gb[0], gc[0],
      gb[1], gc[1], gb[2], gc[2], (float*)d_out, N);
}

// Round 10
// 632.280 us; speedup vs baseline: 3.0849x; 1.0125x over previous
//
#include <hip/hip_runtime.h>

typedef unsigned short u16;
typedef __attribute__((ext_vector_type(8))) short bf16x8;
typedef __attribute__((ext_vector_type(4))) float f32x4;

__device__ inline u16 f2bf(float f) {
  unsigned int u = __float_as_uint(f);
  u += 0x7fffu + ((u >> 16) & 1u);
  return (u16)(u >> 16);
}
__device__ inline float bf2f(u16 v) {
  return __uint_as_float((unsigned)v << 16);
}

__device__ inline uint4 pack8(float4 a, float4 b) {
  uint4 r;
  r.x = (unsigned)f2bf(a.x) | ((unsigned)f2bf(a.y) << 16);
  r.y = (unsigned)f2bf(a.z) | ((unsigned)f2bf(a.w) << 16);
  r.z = (unsigned)f2bf(b.x) | ((unsigned)f2bf(b.y) << 16);
  r.w = (unsigned)f2bf(b.z) | ((unsigned)f2bf(b.w) << 16);
  return r;
}

// ---- fused one-shot weight transpose ----
struct TransDesc {
  const float* src[9];
  u16* dst[9];
  int R[9];
  int C[9];
  int pre[10];
};

__global__ void transpose_all_kernel(TransDesc td) {
  int t = blockIdx.x * 256 + threadIdx.x;
  if (t >= td.pre[9]) return;
  int seg = 0;
  while (t >= td.pre[seg + 1]) ++seg;
  int local = t - td.pre[seg];
  int C = td.C[seg], R = td.R[seg];
  int r = local / C, c = local - r * C;
  td.dst[seg][(size_t)c * R + r] = f2bf(td.src[seg][local]);
}

// ---------------- CSR slot build ----------------
__global__ void count_kernel(const int* __restrict__ fi,
                             const int* __restrict__ ti,
                             int* __restrict__ cnt, int E) {
  int e = blockIdx.x * 256 + threadIdx.x;
  if (e < E) {
    atomicAdd(&cnt[ti[e]], 1);
    atomicAdd(&cnt[fi[e]], 1);
  }
}

__global__ void scan1_kernel(const int* __restrict__ cnt,
                             int* __restrict__ partial, int N, int chunk) {
  __shared__ int sdata[256];
  int b = blockIdx.x, t = threadIdx.x;
  int base = b * chunk;
  int sum = 0;
  for (int i = t; i < chunk; i += 256) {
    int idx = base + i;
    if (idx < N) sum += cnt[idx];
  }
  sdata[t] = sum;
  __syncthreads();
  for (int s2 = 128; s2 > 0; s2 >>= 1) {
    if (t < s2) sdata[t] += sdata[t + s2];
    __syncthreads();
  }
  if (t == 0) partial[b] = sdata[0];
}

__global__ void scan2_kernel(int* __restrict__ partial) {
  __shared__ int s[256];
  int t = threadIdx.x;
  int own = partial[t];
  s[t] = own;
  __syncthreads();
  for (int d2 = 1; d2 < 256; d2 <<= 1) {
    int v = (t >= d2) ? s[t - d2] : 0;
    __syncthreads();
    s[t] += v;
    __syncthreads();
  }
  partial[t] = s[t] - own;  // exclusive
}

__global__ void scan3_kernel(const int* __restrict__ cnt,
                             const int* __restrict__ partialEx,
                             int* __restrict__ cursor, int N, int chunk) {
  __shared__ int s[256];
  int b = blockIdx.x, t = threadIdx.x;
  int base = b * chunk;
  int own = (t < chunk && base + t < N) ? cnt[base + t] : 0;
  s[t] = own;
  __syncthreads();
  for (int d2 = 1; d2 < 256; d2 <<= 1) {
    int v = (t >= d2) ? s[t - d2] : 0;
    __syncthreads();
    s[t] += v;
    __syncthreads();
  }
  int ex = s[t] - own + partialEx[b];
  if (t < chunk && base + t < N) cursor[base + t] = ex;
}

__global__ void slot_kernel(const int* __restrict__ fi,
                            const int* __restrict__ ti,
                            int* __restrict__ cursor, int* __restrict__ s_nbr,
                            int* __restrict__ s_eid, int* __restrict__ s_dest,
                            int E) {
  int e = blockIdx.x * 256 + threadIdx.x;
  if (e < E) {
    int f = fi[e], t2 = ti[e];
    int p0 = atomicAdd(&cursor[t2], 1);
    s_nbr[p0] = f;
    s_eid[p0] = e;
    s_dest[p0] = t2;
    int p1 = atomicAdd(&cursor[f], 1);
    s_nbr[p1] = t2;
    s_eid[p1] = e;
    s_dest[p1] = f;
  }
}

// ---- shared MFMA helpers (verified R1-R9) ----
__device__ inline void stage_w_rw(u16* sW, const u16* __restrict__ src,
                                  int roww, int colofs, int tid) {
  int n = tid >> 1, half = tid & 1;
  const u16* s = src + (size_t)n * roww + colofs + half * 64;
#pragma unroll
  for (int q = 0; q < 8; ++q) {
    uint4 v = *(const uint4*)(s + q * 8);
    int byte = n * 256 + ((half * 128 + q * 16) ^ ((n & 7) << 4));
    *(uint4*)((char*)sW + byte) = v;
  }
}

__device__ inline void stage_w_512(u16* sW, const u16* __restrict__ src,
                                   int roww, int colofs, int tid) {
  int n = tid >> 2, quarter = tid & 3;
  const u16* s = src + (size_t)n * roww + colofs + quarter * 32;
#pragma unroll
  for (int q = 0; q < 4; ++q) {
    uint4 v = *(const uint4*)(s + q * 8);
    int byte = n * 256 + ((quarter * 64 + q * 16) ^ ((n & 7) << 4));
    *(uint4*)((char*)sW + byte) = v;
  }
}

__device__ inline void mfma_pass(const u16* A, const u16* W, f32x4 acc[8],
                                 int w, int lane) {
  const int cA = lane & 15;
  const int ko = (lane >> 4) * 8;
  const int arow = 16 * w + cA;
#pragma unroll
  for (int kk = 0; kk < 4; ++kk) {
    int ka = (kk * 32 + ko) * 2;
    int sx = ka ^ ((cA & 7) << 4);
    bf16x8 a = *(const bf16x8*)((const char*)A + arow * 256 + sx);
#pragma unroll
    for (int nt = 0; nt < 8; ++nt) {
      bf16x8 bb = *(const bf16x8*)((const char*)W + (nt * 16 + cA) * 256 + sx);
      acc[nt] = __builtin_amdgcn_mfma_f32_16x16x32_bf16(a, bb, acc[nt], 0, 0, 0);
    }
  }
}

__device__ inline void write_h_lds(u16* sH, const f32x4 acc[8], int w,
                                   int lane) {
#pragma unroll
  for (int nt = 0; nt < 8; ++nt) {
    int col = nt * 16 + (lane & 15);
#pragma unroll
    for (int i = 0; i < 4; ++i) {
      int rr = 16 * w + ((lane >> 4) * 4) + i;
      *(u16*)((char*)sH + rr * 256 + ((col * 2) ^ ((rr & 7) << 4))) =
          f2bf(acc[nt][i]);
    }
  }
}

// Fused first-layer GEMMs: blocks [0,Nb): Pa/Pb = bf16(ns@W1a/b);
// blocks [Nb, Nb+Eb): EFm = bf16(ef@W1c + b1). 64 rows / 256 threads each.
__global__ __launch_bounds__(256) void gemm1_kernel(
    const float* __restrict__ ns, const float* __restrict__ ef,
    const u16* __restrict__ Wt1, const float* __restrict__ b1,
    u16* __restrict__ Pa, u16* __restrict__ Pb, u16* __restrict__ EFm, int N,
    int E, int Nb) {
  __shared__ u16 sA[64 * 128];
  __shared__ u16 sW[128 * 128];
  const int tid = threadIdx.x;
  const int lane = tid & 63;
  const int w = tid >> 6;
  if ((int)blockIdx.x < Nb) {
    const int r0 = blockIdx.x * 64;
    {
      int row = tid >> 2, seg = tid & 3;
      int rr = r0 + row;
      if (rr >= N) rr = N - 1;
      const float4* sx = (const float4*)(ns + (size_t)rr * 128 + seg * 32);
#pragma unroll
      for (int q = 0; q < 4; ++q) {
        int byte = row * 256 + ((seg * 64 + q * 16) ^ ((row & 7) << 4));
        *(uint4*)((char*)sA + byte) = pack8(sx[q * 2], sx[q * 2 + 1]);
      }
    }
    stage_w_rw(sW, Wt1, 384, 0, tid);
    __syncthreads();
    f32x4 accA[8] = {};
    mfma_pass(sA, sW, accA, w, lane);
    __syncthreads();
    stage_w_rw(sW, Wt1, 384, 128, tid);
    __syncthreads();
    f32x4 accB[8] = {};
    mfma_pass(sA, sW, accB, w, lane);
#pragma unroll
    for (int nt = 0; nt < 8; ++nt) {
      int col = nt * 16 + (lane & 15);
#pragma unroll
      for (int i = 0; i < 4; ++i) {
        int rr = 16 * w + ((lane >> 4) * 4) + i;
        int row = r0 + rr;
        if (row < N) {
          Pa[(size_t)row * 128 + col] = f2bf(accA[nt][i]);
          Pb[(size_t)row * 128 + col] = f2bf(accB[nt][i]);
        }
      }
    }
  } else {
    const int r0 = (blockIdx.x - Nb) * 64;
    {
      int row = tid >> 2, seg = tid & 3;
      int rr = r0 + row;
      if (rr >= E) rr = E - 1;
      const float4* sx = (const float4*)(ef + (size_t)rr * 128 + seg * 32);
#pragma unroll
      for (int q = 0; q < 4; ++q) {
        int byte = row * 256 + ((seg * 64 + q * 16) ^ ((row & 7) << 4));
        *(uint4*)((char*)sA + byte) = pack8(sx[q * 2], sx[q * 2 + 1]);
      }
    }
    stage_w_rw(sW, Wt1, 384, 256, tid);
    __syncthreads();
    f32x4 acc[8] = {};
    mfma_pass(sA, sW, acc, w, lane);
    __syncthreads();
#pragma unroll
    for (int nt = 0; nt < 8; ++nt) {
      int col = nt * 16 + (lane & 15);
      float bv = b1[col];
#pragma unroll
      for (int i = 0; i < 4; ++i) {
        int rr = 16 * w + ((lane >> 4) * 4) + i;
        *(u16*)((char*)sA + rr * 256 + ((col * 2) ^ ((rr & 7) << 4))) =
            f2bf(acc[nt][i] + bv);
      }
    }
    __syncthreads();
#pragma unroll
    for (int it = 0; it < 4; ++it) {
      int task = tid + (it << 8);
      int row = task >> 4, c8 = task & 15;
      int gr = r0 + row;
      if (gr < E) {
        uint4 v = *(const uint4*)((const char*)sA + row * 256 +
                                  ((c8 << 4) ^ ((row & 7) << 4)));
        *(uint4*)(EFm + (size_t)gr * 128 + (c8 << 3)) = v;
      }
    }
  }
}

// Destination-sorted edge MLP, 64 slots/tile, W2/W3 in LDS -> 2 blocks/CU.
__global__ __launch_bounds__(512, 2) void edge_csr2_kernel(
    const u16* __restrict__ EFm, const int* __restrict__ s_nbr,
    const int* __restrict__ s_eid, const int* __restrict__ s_dest,
    const u16* __restrict__ Wt2, const u16* __restrict__ Wt3,
    const u16* __restrict__ Pa, const u16* __restrict__ Pb,
    const float* __restrict__ b2, const float* __restrict__ b3,
    float* __restrict__ aggf, int nslots, int ntiles) {
  __shared__ u16 sW2[128 * 128];  // 32 KB
  __shared__ u16 sW3[128 * 128];  // 32 KB
  __shared__ u16 sH[64 * 128];    // 16 KB -> exactly 80 KB, 2 blocks/CU
  const int tid = threadIdx.x;
  const int lane = tid & 63;
  const int wv = tid >> 6;  // 0..7
  const int mw = wv >> 1;   // rows mw*16..+15
  const int nw = wv & 1;    // cols nw*64..+63
  const int l15 = lane & 15;
  const int lhi = lane >> 4;

  stage_w_512(sW2, Wt2, 128, 0, tid);
  stage_w_512(sW3, Wt3, 128, 0, tid);
  float b2f[4], b3f[4];
#pragma unroll
  for (int nt = 0; nt < 4; ++nt) {
    int col = (nw << 6) + (nt << 4) + l15;
    b2f[nt] = b2[col];
    b3f[nt] = b3[col];
  }
  __syncthreads();

  const int ra = (mw << 4) + l15;  // own H row for D/F

  for (int t = blockIdx.x; t < ntiles; t += gridDim.x) {
    const int r0 = t << 6;  // 64 slots
    // Phase C: H1 = relu(EFm[eid] + Pa[nbr] + Pb[dest]) -> sH
#pragma unroll
    for (int it = 0; it < 2; ++it) {
      int task = tid + (it << 9);
      int row = task >> 4;  // 0..63
      int c8 = task & 15;
      int r = r0 + row;
      int rc = r < nslots ? r : nslots - 1;
      int nbr = s_nbr[rc], eid = s_eid[rc], dst = s_dest[rc];
      uint4 efv = *(const uint4*)(EFm + (size_t)eid * 128 + (c8 << 3));
      uint4 pav = *(const uint4*)(Pa + (size_t)nbr * 128 + (c8 << 3));
      uint4 pbv = *(const uint4*)(Pb + (size_t)dst * 128 + (c8 << 3));
      const u16* pe = (const u16*)&efv;
      const u16* pa = (const u16*)&pav;
      const u16* pb = (const u16*)&pbv;
      unsigned o[4];
#pragma unroll
      for (int j = 0; j < 4; ++j) {
        float v0 = fmaxf(bf2f(pe[2 * j]) + bf2f(pa[2 * j]) + bf2f(pb[2 * j]), 0.f);
        float v1 = fmaxf(bf2f(pe[2 * j + 1]) + bf2f(pa[2 * j + 1]) + bf2f(pb[2 * j + 1]), 0.f);
        o[j] = (unsigned)f2bf(v0) | ((unsigned)f2bf(v1) << 16);
      }
      *(uint4*)((char*)sH + row * 256 + ((c8 << 4) ^ ((row & 7) << 4))) = *(uint4*)o;
    }
    __syncthreads();  // B1: H1 ready
    // Phase D: acc = H1(own 16 rows) @ W2 (B-frags from LDS)
    bf16x8 hA[4];
#pragma unroll
    for (int kk = 0; kk < 4; ++kk) {
      int sx = ((kk << 6) + (lhi << 4)) ^ ((ra & 7) << 4);
      hA[kk] = *(const bf16x8*)((const char*)sH + ra * 256 + sx);
    }
    f32x4 acc[4] = {};
#pragma unroll
    for (int kk = 0; kk < 4; ++kk) {
#pragma unroll
      for (int nt = 0; nt < 4; ++nt) {
        int c = (nw << 6) + (nt << 4) + l15;
        int sx = ((kk << 6) + (lhi << 4)) ^ ((c & 7) << 4);
        bf16x8 bb = *(const bf16x8*)((const char*)sW2 + c * 256 + sx);
        acc[nt] = __builtin_amdgcn_mfma_f32_16x16x32_bf16(hA[kk], bb, acc[nt], 0, 0, 0);
      }
    }
    __syncthreads();  // B2: D reads done
    // Phase E: H2 = relu(acc + b2) -> own rows/cols; re-zero acc
#pragma unroll
    for (int i = 0; i < 4; ++i) {
      int rl = (mw << 4) + (lhi << 2) + i;
#pragma unroll
      for (int nt = 0; nt < 4; ++nt) {
        int col = (nw << 6) + (nt << 4) + l15;
        float v = fmaxf(acc[nt][i] + b2f[nt], 0.f);
        *(u16*)((char*)sH + rl * 256 + ((col * 2) ^ ((rl & 7) << 4))) = f2bf(v);
        acc[nt][i] = 0.f;
      }
    }
    __syncthreads();  // B3: H2 ready
    // Phase F: acc = H2 @ W3
#pragma unroll
    for (int kk = 0; kk < 4; ++kk) {
      int sx = ((kk << 6) + (lhi << 4)) ^ ((ra & 7) << 4);
      hA[kk] = *(const bf16x8*)((const char*)sH + ra * 256 + sx);
    }
#pragma unroll
    for (int kk = 0; kk < 4; ++kk) {
#pragma unroll
      for (int nt = 0; nt < 4; ++nt) {
        int c = (nw << 6) + (nt << 4) + l15;
        int sx = ((kk << 6) + (lhi << 4)) ^ ((c & 7) << 4);
        bf16x8 bb = *(const bf16x8*)((const char*)sW3 + c * 256 + sx);
        acc[nt] = __builtin_amdgcn_mfma_f32_16x16x32_bf16(hA[kk], bb, acc[nt], 0, 0, 0);
      }
    }
    __syncthreads();  // B4: F reads done
    // OUT = acc + b3 -> sH
#pragma unroll
    for (int i = 0; i < 4; ++i) {
      int rl = (mw << 4) + (lhi << 2) + i;
#pragma unroll
      for (int nt = 0; nt < 4; ++nt) {
        int col = (nw << 6) + (nt << 4) + l15;
        *(u16*)((char*)sH + rl * 256 + ((col * 2) ^ ((rl & 7) << 4))) =
            f2bf(acc[nt][i] + b3f[nt]);
      }
    }
    __syncthreads();  // B5: OUT ready
    // Segment reduction: thread (col c, quarter q) scans 16 rows (dest-sorted)
    {
      int c = tid & 127, q = tid >> 7;
      float s = 0.f;
      int prev = -1;
      int rbeg = q << 4;
#pragma unroll 4
      for (int rr = rbeg; rr < rbeg + 16; ++rr) {
        int r = r0 + rr;
        int d = (r < nslots) ? s_dest[r] : -1;
        if (d != prev) {
          if (prev >= 0) unsafeAtomicAdd(&aggf[(size_t)prev * 128 + c], s);
          prev = d;
          s = 0.f;
        }
        if (d >= 0)
          s += bf2f(*(const u16*)((const char*)sH + rr * 256 +
                                  ((c * 2) ^ ((rr & 7) << 4))));
      }
      if (prev >= 0) unsafeAtomicAdd(&aggf[(size_t)prev * 128 + c], s);
    }
    __syncthreads();  // B6: sH free
  }
}

// Fused 3-GRU chain, 512 threads / 128 rows (half the serial phases per row)
__global__ __launch_bounds__(512, 1) void gru3_kernel(
    const float* __restrict__ ns, const float* __restrict__ aggf,
    const u16* __restrict__ g0W, const u16* __restrict__ g0U,
    const u16* __restrict__ g1W, const u16* __restrict__ g1U,
    const u16* __restrict__ g2W, const u16* __restrict__ g2U,
    const float* __restrict__ b0, const float* __restrict__ c0,
    const float* __restrict__ b1, const float* __restrict__ c1,
    const float* __restrict__ b2, const float* __restrict__ c2,
    float* __restrict__ out, int N) {
  __shared__ u16 sX[128 * 128];  // 32 KB: ns -> h1
  __shared__ u16 sG[128 * 128];  // 32 KB: agg -> h2
  __shared__ u16 sW[128 * 128];  // 32 KB
  const int tid = threadIdx.x;
  const int lane = tid & 63;
  const int w = tid >> 6;  // 0..7
  const int r0 = blockIdx.x * 128;
  {
    int row = tid >> 2, seg = tid & 3;
    int rr = r0 + row;
    if (rr >= N) rr = N - 1;
    const float4* sx = (const float4*)(ns + (size_t)rr * 128 + seg * 32);
    const float4* sh = (const float4*)(aggf + (size_t)rr * 128 + seg * 32);
#pragma unroll
    for (int q = 0; q < 4; ++q) {
      int byte = row * 256 + ((seg * 64 + q * 16) ^ ((row & 7) << 4));
      *(uint4*)((char*)sX + byte) = pack8(sx[q * 2], sx[q * 2 + 1]);
      *(uint4*)((char*)sG + byte) = pack8(sh[q * 2], sh[q * 2 + 1]);
    }
  }

  float hpf[8][4];

#define GPASS(SRC, ABUF, ACC)                       \
  __syncthreads();                                  \
  stage_w_512(sW, (SRC), 128, 0, tid);              \
  __syncthreads();                                  \
  mfma_pass((ABUF), sW, (ACC), w, lane);

  {
    f32x4 ar[8] = {}, az[8] = {}, ai[8] = {}, ah[8] = {};
    GPASS(g0W + 0 * 16384, sX, ar)
    GPASS(g0U + 0 * 16384, sG, ar)
    GPASS(g0W + 1 * 16384, sX, az)
    GPASS(g0U + 1 * 16384, sG, az)
    GPASS(g0W + 2 * 16384, sX, ai)
    GPASS(g0U + 2 * 16384, sG, ah)
    f32x4 h1[8];
#pragma unroll
    for (int nt = 0; nt < 8; ++nt) {
      int col = nt * 16 + (lane & 15);
      float brc = b0[col] + c0[col];
      float bzc = b0[128 + col] + c0[128 + col];
      float bi = b0[256 + col];
      float bc2 = c0[256 + col];
#pragma unroll
      for (int i = 0; i < 4; ++i) {
        int rloc = 16 * w + ((lane >> 4) * 4) + i;
        int row = r0 + rloc;
        int rowc = row < N ? row : N - 1;
        float hf = aggf[(size_t)rowc * 128 + col];
        float rg = 1.f / (1.f + __expf(-(ar[nt][i] + brc)));
        float zg = 1.f / (1.f + __expf(-(az[nt][i] + bzc)));
        float pre = ai[nt][i] + bi + rg * (ah[nt][i] + bc2);
        float ng = 2.f / (1.f + __expf(-2.f * pre)) - 1.f;
        float hv = (1.f - zg) * ng + zg * hf;
        h1[nt][i] = hv;
        hpf[nt][i] = hv;
      }
    }
    write_h_lds(sX, h1, w, lane);
  }
  {
    f32x4 ar[8] = {}, az[8] = {}, ai[8] = {}, ah[8] = {};
    GPASS(g1W + 0 * 16384, sG, ar)
    GPASS(g1U + 0 * 16384, sX, ar)
    GPASS(g1W + 1 * 16384, sG, az)
    GPASS(g1U + 1 * 16384, sX, az)
    GPASS(g1W + 2 * 16384, sG, ai)
    GPASS(g1U + 2 * 16384, sX, ah)
    f32x4 h2[8];
#pragma unroll
    for (int nt = 0; nt < 8; ++nt) {
      int col = nt * 16 + (lane & 15);
      float brc = b1[col] + c1[col];
      float bzc = b1[128 + col] + c1[128 + col];
      float bi = b1[256 + col];
      float bc2 = c1[256 + col];
#pragma unroll
      for (int i = 0; i < 4; ++i) {
        float rg = 1.f / (1.f + __expf(-(ar[nt][i] + brc)));
        float zg = 1.f / (1.f + __expf(-(az[nt][i] + bzc)));
        float pre = ai[nt][i] + bi + rg * (ah[nt][i] + bc2);
        float ng = 2.f / (1.f + __expf(-2.f * pre)) - 1.f;
        float hv = (1.f - zg) * ng + zg * hpf[nt][i];
        h2[nt][i] = hv;
        hpf[nt][i] = hv;
      }
    }
    write_h_lds(sG, h2, w, lane);
  }
  {
    f32x4 ar[8] = {}, az[8] = {}, ai[8] = {}, ah[8] = {};
    GPASS(g2W + 0 * 16384, sX, ar)
    GPASS(g2U + 0 * 16384, sG, ar)
    GPASS(g2W + 1 * 16384, sX, az)
    GPASS(g2U + 1 * 16384, sG, az)
    GPASS(g2W + 2 * 16384, sX, ai)
    GPASS(g2U + 2 * 16384, sG, ah)
#pragma unroll
    for (int nt = 0; nt < 8; ++nt) {
      int col = nt * 16 + (lane & 15);
      float brc = b2[col] + c2[col];
      float bzc = b2[128 + col] + c2[128 + col];
      float bi = b2[256 + col];
      float bc2 = c2[256 + col];
#pragma unroll
      for (int i = 0; i < 4; ++i) {
        int rloc = 16 * w + ((lane >> 4) * 4) + i;
        int row = r0 + rloc;
        if (row < N) {
          float rg = 1.f / (1.f + __expf(-(ar[nt][i] + brc)));
          float zg = 1.f / (1.f + __expf(-(az[nt][i] + bzc)));
          float pre = ai[nt][i] + bi + rg * (ah[nt][i] + bc2);
          float ng = 2.f / (1.f + __expf(-2.f * pre)) - 1.f;
          out[(size_t)row * 128 + col] = (1.f - zg) * ng + zg * hpf[nt][i];
        }
      }
    }
  }
#undef GPASS
}

extern "C" void kernel_launch(void* const* d_in, const int* in_sizes, int n_in,
                              void* d_out, int out_size, void* d_ws,
                              size_t ws_size, hipStream_t stream) {
  const float* ns = (const float*)d_in[0];
  const float* ef = (const float*)d_in[1];
  const int* from_idx = (const int*)d_in[2];
  const int* to_idx = (const int*)d_in[3];
  const float* mW1 = (const float*)d_in[5];
  const float* mb1 = (const float*)d_in[6];
  const float* mW2 = (const float*)d_in[7];
  const float* mb2 = (const float*)d_in[8];
  const float* mW3 = (const float*)d_in[9];
  const float* mb3 = (const float*)d_in[10];
  const float* gW[3] = {(const float*)d_in[11], (const float*)d_in[15], (const float*)d_in[19]};
  const float* gU[3] = {(const float*)d_in[12], (const float*)d_in[16], (const float*)d_in[20]};
  const float* gb[3] = {(const float*)d_in[13], (const float*)d_in[17], (const float*)d_in[21]};
  const float* gc[3] = {(const float*)d_in[14], (const float*)d_in[18], (const float*)d_in[22]};

  const int N = in_sizes[0] / 128;
  const int E = in_sizes[1] / 128;
  const int nslots = 2 * E;

  char* base = (char*)d_ws;
  size_t cur = 0;
  auto alloc = [&](size_t bytes) {
    size_t p = cur;
    cur = (cur + bytes + 255) & ~(size_t)255;
    return (void*)(base + p);
  };
  float* aggf = (float*)alloc((size_t)N * 128 * 4);
  u16* Pa = (u16*)alloc((size_t)N * 128 * 2);
  u16* Pb = (u16*)alloc((size_t)N * 128 * 2);
  u16* Wt1 = (u16*)alloc(384 * 128 * 2);
  u16* Wt2 = (u16*)alloc(128 * 128 * 2);
  u16* Wt3 = (u16*)alloc(128 * 128 * 2);
  u16 *gWt[3], *gUt[3];
  for (int i = 0; i < 3; ++i) {
    gWt[i] = (u16*)alloc(384 * 128 * 2);
    gUt[i] = (u16*)alloc(384 * 128 * 2);
  }
  int* cnt = (int*)alloc((size_t)N * 4);
  int* cursor = (int*)alloc((size_t)N * 4);
  int* partial = (int*)alloc(256 * 4);
  int* s_nbr = (int*)alloc((size_t)nslots * 4);
  int* s_eid = (int*)alloc((size_t)nslots * 4);
  int* s_dest = (int*)alloc((size_t)nslots * 4);
  u16* EFm = (u16*)alloc((size_t)E * 128 * 2);
  (void)ws_size;  // ~193 MB total

  {
    TransDesc td;
    const float* srcs[9] = {mW1, mW2, mW3, gW[0], gU[0], gW[1], gU[1], gW[2], gU[2]};
    u16* dsts[9] = {Wt1, Wt2, Wt3, gWt[0], gUt[0], gWt[1], gUt[1], gWt[2], gUt[2]};
    int Rs[9] = {384, 128, 128, 128, 128, 128, 128, 128, 128};
    int Cs[9] = {128, 128, 128, 384, 384, 384, 384, 384, 384};
    int acc = 0;
    for (int i = 0; i < 9; ++i) {
      td.src[i] = srcs[i];
      td.dst[i] = dsts[i];
      td.R[i] = Rs[i];
      td.C[i] = Cs[i];
      td.pre[i] = acc;
      acc += Rs[i] * Cs[i];
    }
    td.pre[9] = acc;
    transpose_all_kernel<<<(acc + 255) / 256, 256, 0, stream>>>(td);
  }

  // CSR slot build
  hipMemsetAsync(cnt, 0, (size_t)N * 4, stream);
  count_kernel<<<(E + 255) / 256, 256, 0, stream>>>(from_idx, to_idx, cnt, E);
  int chunk = (N + 255) / 256;
  scan1_kernel<<<256, 256, 0, stream>>>(cnt, partial, N, chunk);
  scan2_kernel<<<1, 256, 0, stream>>>(partial);
  scan3_kernel<<<256, 256, 0, stream>>>(cnt, partial, cursor, N, chunk);
  slot_kernel<<<(E + 255) / 256, 256, 0, stream>>>(from_idx, to_idx, cursor,
                                                   s_nbr, s_eid, s_dest, E);

  // fused first-layer GEMMs (node partials + EF)
  int Nb = (N + 63) / 64, Eb = (E + 63) / 64;
  gemm1_kernel<<<Nb + Eb, 256, 0, stream>>>(ns, ef, Wt1, mb1, Pa, Pb, EFm, N,
                                            E, Nb);

  // destination-sorted edge MLP + fused aggregation
  hipMemsetAsync(aggf, 0, (size_t)N * 128 * 4, stream);
  int ntiles = (nslots + 63) / 64;
  int egrid = ntiles < 512 ? ntiles : 512;
  edge_csr2_kernel<<<egrid, 512, 0, stream>>>(EFm, s_nbr, s_eid, s_dest, Wt2,
                                              Wt3, Pa, Pb, mb2, mb3, aggf,
                                              nslots, ntiles);

  int gblocks = (N + 127) / 128;
  gru3_kernel<<<gblocks, 512, 0, stream>>>(
      ns, aggf, gWt[0], gUt[0], gWt[1], gUt[1], gWt[2], gUt[2], gb[0], gc[0],
      gb[1], gc[1], gb[2], gc[2], (float*)d_out, N);
}